// Round 4
// baseline (374.996 us; speedup 1.0000x reference)
//
#include <hip/hip_runtime.h>
#include <math.h>

// Problem constants (fixed by the reference)
#define HD 512          // Q_DIM = F_DIM = H_DIM = OUT_DIM = 512
#define SP 129          // S+1 = T+1
#define RPAD 144        // padded key rows per batch (129 used, rest zero; 9x16)
#define ROWS 144
#define NBATCH 16
#define MQ 4096         // 16*256 query rows
#define SCALE 0.04419417382415922f  // 1/sqrt(512)

typedef _Float16 f16;
typedef _Float16 f16x8 __attribute__((ext_vector_type(8)));
typedef _Float16 f16x4 __attribute__((ext_vector_type(4)));
typedef _Float16 f16x2 __attribute__((ext_vector_type(2)));
typedef float f32x4  __attribute__((ext_vector_type(4)));

// ---------------------------------------------------------------------------
// flat f32 -> f16 convert (8 elems/thread)
// ---------------------------------------------------------------------------
__global__ __launch_bounds__(256) void conv_f32_f16(
    const float* __restrict__ a, f16* __restrict__ o, int n)
{
  int base = (blockIdx.x * 256 + threadIdx.x) * 8;
  if (base < n) {
    float4 x = *(const float4*)(a + base);
    float4 y = *(const float4*)(a + base + 4);
    f16x8 v = { (f16)x.x, (f16)x.y, (f16)x.z, (f16)x.w,
                (f16)y.x, (f16)y.y, (f16)y.z, (f16)y.w };
    *(f16x8*)(o + base) = v;
  }
}

// ---------------------------------------------------------------------------
// W[K][N] f32 -> WT[N][K] f16 (transpose + convert), 64x64 LDS tiles
// ---------------------------------------------------------------------------
__global__ __launch_bounds__(256) void convT_f32_f16(
    const float* __restrict__ W, f16* __restrict__ WT, int K, int N)
{
  __shared__ float t[64][65];
  const int k0 = blockIdx.x * 64, n0 = blockIdx.y * 64;
  const int tid = threadIdx.x;
  const int r = tid >> 4, c4 = (tid & 15) * 4;
  #pragma unroll
  for (int i = 0; i < 4; ++i) {
    int k = r + 16*i;
    float4 v = *(const float4*)(W + (size_t)(k0 + k)*N + n0 + c4);
    t[k][c4] = v.x; t[k][c4+1] = v.y; t[k][c4+2] = v.z; t[k][c4+3] = v.w;
  }
  __syncthreads();
  #pragma unroll
  for (int i = 0; i < 4; ++i) {
    int n = r + 16*i;
    f16x4 v = { (f16)t[c4][n], (f16)t[c4+1][n], (f16)t[c4+2][n], (f16)t[c4+3][n] };
    *(f16x4*)(WT + (size_t)(n0 + n)*K + k0 + c4) = v;
  }
}

// ---------------------------------------------------------------------------
// f16 MFMA GEMM: C[M,N] = concat_seg(A)[M, NSEG*512] @ WT^T + bias
// MODE 0: f16 out; MODE 1: f16 out + key row remap (128/batch -> 144/batch);
// MODE 2: f32 out with tanh.
// ---------------------------------------------------------------------------
template<int NSEG, int MODE>
__global__ __launch_bounds__(256) void gemm_f16(
    const f16* __restrict__ A0, const f16* __restrict__ A1,
    const f16* __restrict__ A2, const f16* __restrict__ WT,
    const float* __restrict__ bias, void* __restrict__ Cv, int M, int N)
{
  __shared__ __align__(16) f16 As[64*64];
  __shared__ __align__(16) f16 Bs[64*64];
  const int KTOT = NSEG * 512;
  const int tid  = threadIdx.x;
  const int lane = tid & 63;
  const int w    = tid >> 6;
  const int wr   = w & 1, wc = w >> 1;
  const int fq   = lane >> 4, fr = lane & 15;
  const int bm = blockIdx.x * 64, bn = blockIdx.y * 64;

  f32x4 acc[2][2] = {};

  for (int k0 = 0; k0 < KTOT; k0 += 64) {
    const int seg  = k0 >> 9;
    const f16* Ap  = (NSEG == 1) ? A0 : (seg == 0 ? A0 : (seg == 1 ? A1 : A2));
    const int kloc = k0 & 511;
    #pragma unroll
    for (int i = 0; i < 2; ++i) {
      int idx = tid + 256*i;
      int r = idx >> 3, c = idx & 7;
      const uint4 va = *(const uint4*)(Ap + (size_t)(bm + r)*512 + kloc + c*8);
      const uint4 vb = *(const uint4*)(WT + (size_t)(bn + r)*KTOT + k0 + c*8);
      int o = ((r << 7) + (c << 4)) ^ ((r & 7) << 4);
      *(uint4*)((char*)As + o) = va;
      *(uint4*)((char*)Bs + o) = vb;
    }
    __syncthreads();
    #pragma unroll
    for (int ks = 0; ks < 2; ++ks) {
      f16x8 af[2], bf_[2];
      #pragma unroll
      for (int i = 0; i < 2; ++i) {
        int ra = wr*32 + i*16 + fr;
        int oa = ((ra << 7) + (ks << 6) + (fq << 4)) ^ ((ra & 7) << 4);
        af[i] = *(const f16x8*)((const char*)As + oa);
        int rb = wc*32 + i*16 + fr;
        int ob = ((rb << 7) + (ks << 6) + (fq << 4)) ^ ((rb & 7) << 4);
        bf_[i] = *(const f16x8*)((const char*)Bs + ob);
      }
      #pragma unroll
      for (int i = 0; i < 2; ++i)
        #pragma unroll
        for (int j = 0; j < 2; ++j)
          acc[i][j] = __builtin_amdgcn_mfma_f32_16x16x32_f16(af[i], bf_[j], acc[i][j], 0, 0, 0);
    }
    __syncthreads();
  }

  #pragma unroll
  for (int i = 0; i < 2; ++i) {
    #pragma unroll
    for (int j = 0; j < 2; ++j) {
      int n = bn + wc*32 + j*16 + fr;
      float bv = bias[n];
      #pragma unroll
      for (int r = 0; r < 4; ++r) {
        int m = bm + wr*32 + i*16 + fq*4 + r;
        float x = acc[i][j][r] + bv;
        if (MODE == 0) {
          ((f16*)Cv)[(size_t)m*N + n] = (f16)x;
        } else if (MODE == 1) {
          int mo = (m >> 7) * RPAD + (m & 127);
          ((f16*)Cv)[(size_t)mo*N + n] = (f16)x;
        } else {
          x = fminf(fmaxf(x, -20.f), 20.f);
          float e = __expf(2.0f * x);
          ((float*)Cv)[(size_t)m*N + n] = (e - 1.0f) / (e + 1.0f);
        }
      }
    }
  }
}

// Rows 128..143 of each batch: row 128 = bias (reference pad row), rest 0.
__global__ void write_pad_f16(f16* __restrict__ skey, const float* __restrict__ bs,
                              f16* __restrict__ tkey, const float* __restrict__ bt)
{
  int i = blockIdx.x * 256 + threadIdx.x;   // 16 batches * 16 rows * 512
  int b = i >> 13;
  int r = 128 + ((i >> 9) & 15);
  int k = i & 511;
  size_t off = ((size_t)b*RPAD + r)*HD + k;
  skey[off] = (r == 128) ? (f16)bs[k] : (f16)0.f;
  tkey[off] = (r == 128) ? (f16)bt[k] : (f16)0.f;
}

// ---------------------------------------------------------------------------
// Fused trilinear attention, f16 MFMA. 512 threads / 8 waves; 2 query rows
// per block (staging shared). Per row: 9x9 tile grid (144x144), 4 waves in a
// {5,4}x{5,4} quadrant split. T14 async staging: global loads for tile k+1
// issued before MFMA(k). P never materialized: only gmax, row sums ws, col
// sums wt; s_ctx = (ws/Z)@s_key, t_ctx = (wt/Z)@t_key.
// ---------------------------------------------------------------------------
__global__ __launch_bounds__(512, 2) void attn_kernel(
    const f16* __restrict__ qg,      // (4096, 512)
    const f16* __restrict__ s_key,   // (16, 144, 512)
    const f16* __restrict__ t_key,   // (16, 144, 512)
    f16* __restrict__ s_ctx,         // (4096, 512)
    f16* __restrict__ t_ctx)         // (4096, 512)
{
  __shared__ __align__(16) f16 KB0[ROWS*64];   // s_key K-tile, XOR-swizzled
  __shared__ __align__(16) f16 KB1[ROWS*64];   // t_key K-tile
  __shared__ __align__(16) f16 qs[2][HD];
  __shared__ float wsum[2][2][2][ROWS];  // [ws|wt][qrow][half][s]
  __shared__ float red[16];
  __shared__ float invZs[2];

  const int tid  = threadIdx.x;
  const int lane = tid & 63;
  const int w    = tid >> 6;
  const int qrow = w >> 2;
  const int quad = w & 3;
  const int rb   = quad & 1;         // row-half: ti 0..4 / 5..8
  const int cb   = quad >> 1;        // col-half: tj 0..4 / 5..8
  const int tibase = rb ? 5 : 0, nr = rb ? 4 : 5;
  const int tjbase = cb ? 5 : 0, nc = cb ? 4 : 5;
  const int fq = lane >> 4, fr = lane & 15;

  // XCD-chunked swizzle: 2048 blocks -> 256 consecutive pairs per XCD
  const int pair = ((int)blockIdx.x & 7) * 256 + ((int)blockIdx.x >> 3);
  const int gid0 = pair * 2;
  const int b    = gid0 >> 8;
  const f16* skg = s_key + (size_t)b * RPAD * HD;
  const f16* tkg = t_key + (size_t)b * RPAD * HD;

  // load both query rows into LDS
  if (tid < 128) {
    int row = tid >> 6, n = tid & 63;
    *(uint4*)(&qs[row][n*8]) = *(const uint4*)(qg + (size_t)(gid0 + row)*HD + n*8);
  }

  // staging: 1152 16B-tasks per key; thread tasks {tid, tid+512, tid+1024<128}
  uint4 va[3], vb[3];
  auto stage_load = [&](int kt) {
    const int k0 = kt * 64;
    #pragma unroll
    for (int n = 0; n < 3; ++n) {
      if (n < 2 || tid < 128) {
        int t = tid + 512*n;
        int r = t >> 3, c = t & 7;
        size_t g = (size_t)r*HD + k0 + c*8;
        va[n] = *(const uint4*)(skg + g);
        vb[n] = *(const uint4*)(tkg + g);
      }
    }
  };
  auto stage_write = [&]() {
    #pragma unroll
    for (int n = 0; n < 3; ++n) {
      if (n < 2 || tid < 128) {
        int t = tid + 512*n;
        int r = t >> 3, c = t & 7;
        int o = ((r << 7) + (c << 4)) ^ ((r & 7) << 4);
        *(uint4*)((char*)KB0 + o) = va[n];
        *(uint4*)((char*)KB1 + o) = vb[n];
      }
    }
  };

  f32x4 acc[5][5] = {};

  auto mfma_step = [&](int kt) {
    #pragma unroll
    for (int ks = 0; ks < 2; ++ks) {
      const f16x8 qv = *(const f16x8*)(&qs[qrow][kt*64 + ks*32 + fq*8]);
      f16x8 bfv[5];
      #pragma unroll
      for (int j = 0; j < 5; ++j) if (j < nc) {
        int rt = 16*(tjbase + j) + fr;
        int ob = ((rt << 7) + (ks << 6) + (fq << 4)) ^ ((rt & 7) << 4);
        bfv[j] = *(const f16x8*)((const char*)KB1 + ob);
      }
      __builtin_amdgcn_s_setprio(1);
      #pragma unroll
      for (int i = 0; i < 5; ++i) if (i < nr) {
        int rs = 16*(tibase + i) + fr;
        int oa = ((rs << 7) + (ks << 6) + (fq << 4)) ^ ((rs & 7) << 4);
        f16x8 a = *(const f16x8*)((const char*)KB0 + oa) * qv;  // v_pk_mul_f16
        #pragma unroll
        for (int j = 0; j < 5; ++j) if (j < nc)
          acc[i][j] = __builtin_amdgcn_mfma_f32_16x16x32_f16(a, bfv[j], acc[i][j], 0, 0, 0);
      }
      __builtin_amdgcn_s_setprio(0);
    }
  };

  // prologue: stage tile 0
  stage_load(0);
  stage_write();
  __syncthreads();

  for (int kt = 0; kt < 8; ++kt) {
    if (kt < 7) stage_load(kt + 1);   // issue early: latency hides under MFMA
    mfma_step(kt);
    __syncthreads();                   // all reads of the buffer done
    if (kt < 7) stage_write();
    __syncthreads();                   // writes visible before next reads
  }

  // ---- masked max over valid (s<=128, t<=128) ----
  float m = -3e38f;
  #pragma unroll
  for (int i = 0; i < 5; ++i) if (i < nr) {
    #pragma unroll
    for (int j = 0; j < 5; ++j) if (j < nc) {
      #pragma unroll
      for (int r = 0; r < 4; ++r) {
        int s = 16*(tibase + i) + fq*4 + r;
        int t = 16*(tjbase + j) + fr;
        bool ok = (s <= 128) && (t <= 128);
        m = ok ? fmaxf(m, acc[i][j][r]) : m;
      }
    }
  }
  #pragma unroll
  for (int off = 32; off > 0; off >>= 1) m = fmaxf(m, __shfl_xor(m, off));
  if (lane == 0) red[w] = m;
  __syncthreads();
  const float gmax = fmaxf(fmaxf(red[qrow*4], red[qrow*4+1]),
                           fmaxf(red[qrow*4+2], red[qrow*4+3])) * SCALE;

  // ---- exp in registers (invalid -> 0) ----
  #pragma unroll
  for (int i = 0; i < 5; ++i) if (i < nr) {
    #pragma unroll
    for (int j = 0; j < 5; ++j) if (j < nc) {
      #pragma unroll
      for (int r = 0; r < 4; ++r) {
        int s = 16*(tibase + i) + fq*4 + r;
        int t = 16*(tjbase + j) + fr;
        bool ok = (s <= 128) && (t <= 128);
        float p = __expf(acc[i][j][r] * SCALE - gmax);
        acc[i][j][r] = ok ? p : 0.0f;
      }
    }
  }

  // ---- ws: row sums over this wave's cols; reduce across fr ----
  #pragma unroll
  for (int i = 0; i < 5; ++i) if (i < nr) {
    #pragma unroll
    for (int r = 0; r < 4; ++r) {
      float rs = 0.f;
      #pragma unroll
      for (int j = 0; j < 5; ++j) if (j < nc) rs += acc[i][j][r];
      rs += __shfl_xor(rs, 1); rs += __shfl_xor(rs, 2);
      rs += __shfl_xor(rs, 4); rs += __shfl_xor(rs, 8);
      if (fr == 0) wsum[0][qrow][cb][16*(tibase + i) + fq*4 + r] = rs;
    }
  }
  // ---- wt: col sums over this wave's rows; reduce across fq ----
  #pragma unroll
  for (int j = 0; j < 5; ++j) if (j < nc) {
    float cs = 0.f;
    #pragma unroll
    for (int i = 0; i < 5; ++i) if (i < nr) {
      #pragma unroll
      for (int r = 0; r < 4; ++r) cs += acc[i][j][r];
    }
    cs += __shfl_xor(cs, 16); cs += __shfl_xor(cs, 32);
    if (fq == 0) wsum[1][qrow][rb][16*(tjbase + j) + fr] = cs;
  }
  __syncthreads();

  // ---- Z per query row ----
  {
    int qr2 = tid >> 8, s = tid & 255;
    float zv = (s < ROWS) ? (wsum[0][qr2][0][s] + wsum[0][qr2][1][s]) : 0.f;
    #pragma unroll
    for (int off = 32; off > 0; off >>= 1) zv += __shfl_xor(zv, off);
    if (lane == 0) red[8 + w] = zv;
  }
  __syncthreads();
  if (tid < 2)
    invZs[tid] = 1.0f / (red[8 + tid*4] + red[9 + tid*4] + red[10 + tid*4] + red[11 + tid*4]);
  __syncthreads();

  // ---- contexts: thread = (key-type, k-pair), both query rows ----
  {
    const int ksel = tid >> 8;            // 0: s_ctx, 1: t_ctx
    const int k2 = (tid & 255) * 2;
    const f16* kg = ksel ? tkg : skg;
    float a00 = 0.f, a01 = 0.f, a10 = 0.f, a11 = 0.f;
    for (int s = 0; s < SP; ++s) {
      float w0 = wsum[ksel][0][0][s] + wsum[ksel][0][1][s];
      float w1 = wsum[ksel][1][0][s] + wsum[ksel][1][1][s];
      f16x2 kv = *(const f16x2*)(kg + (size_t)s*HD + k2);
      float kf0 = (float)kv[0], kf1 = (float)kv[1];
      a00 = fmaf(w0, kf0, a00); a01 = fmaf(w0, kf1, a01);
      a10 = fmaf(w1, kf0, a10); a11 = fmaf(w1, kf1, a11);
    }
    const float z0 = invZs[0], z1 = invZs[1];
    f16* dst = ksel ? t_ctx : s_ctx;
    f16x2 o0 = { (f16)(a00 * z0), (f16)(a01 * z0) };
    f16x2 o1 = { (f16)(a10 * z1), (f16)(a11 * z1) };
    *(f16x2*)(dst + (size_t)gid0*HD + k2) = o0;
    *(f16x2*)(dst + (size_t)(gid0 + 1)*HD + k2) = o1;
  }
}

extern "C" void kernel_launch(void* const* d_in, const int* in_sizes, int n_in,
                              void* d_out, int out_size, void* d_ws, size_t ws_size,
                              hipStream_t stream) {
  (void)in_sizes; (void)n_in; (void)out_size; (void)ws_size;
  const float* query = (const float*)d_in[0];
  const float* src   = (const float*)d_in[1];
  const float* trg   = (const float*)d_in[2];
  const float* Wq    = (const float*)d_in[3];
  const float* bq    = (const float*)d_in[4];
  const float* Wsm   = (const float*)d_in[5];
  const float* bs    = (const float*)d_in[6];
  const float* Wtm   = (const float*)d_in[7];
  const float* bt    = (const float*)d_in[8];
  const float* Wo    = (const float*)d_in[9];
  const float* bo    = (const float*)d_in[10];
  float* out = (float*)d_out;

  // workspace layout (f16 buffers)
  char* p = (char*)d_ws;
  f16* query_h = (f16*)p;                 p += (size_t)MQ*HD*2;
  f16* src_h   = (f16*)p;                 p += (size_t)2048*HD*2;
  f16* trg_h   = (f16*)p;                 p += (size_t)2048*HD*2;
  f16* WqT     = (f16*)p;                 p += (size_t)HD*HD*2;
  f16* WsT     = (f16*)p;                 p += (size_t)HD*HD*2;
  f16* WtT     = (f16*)p;                 p += (size_t)HD*HD*2;
  f16* WoT     = (f16*)p;                 p += (size_t)1536*HD*2;
  f16* q_h     = (f16*)p;                 p += (size_t)MQ*HD*2;
  f16* skey    = (f16*)p;                 p += (size_t)NBATCH*RPAD*HD*2;
  f16* tkey    = (f16*)p;                 p += (size_t)NBATCH*RPAD*HD*2;
  f16* sctx    = (f16*)p;                 p += (size_t)MQ*HD*2;
  f16* tctx    = (f16*)p;                 p += (size_t)MQ*HD*2;

  dim3 blk(256);
  conv_f32_f16<<<dim3(MQ*HD/8/256), blk, 0, stream>>>(query, query_h, MQ*HD);
  conv_f32_f16<<<dim3(2048*HD/8/256), blk, 0, stream>>>(src, src_h, 2048*HD);
  conv_f32_f16<<<dim3(2048*HD/8/256), blk, 0, stream>>>(trg, trg_h, 2048*HD);
  convT_f32_f16<<<dim3(8, 8), blk, 0, stream>>>(Wq, WqT, HD, HD);
  convT_f32_f16<<<dim3(8, 8), blk, 0, stream>>>(Wsm, WsT, HD, HD);
  convT_f32_f16<<<dim3(8, 8), blk, 0, stream>>>(Wtm, WtT, HD, HD);
  convT_f32_f16<<<dim3(24, 8), blk, 0, stream>>>(Wo, WoT, 1536, HD);

  gemm_f16<1,0><<<dim3(64, 8), blk, 0, stream>>>(query_h, nullptr, nullptr, WqT, bq, q_h, MQ, HD);
  gemm_f16<1,1><<<dim3(32, 8), blk, 0, stream>>>(src_h, nullptr, nullptr, WsT, bs, skey, 2048, HD);
  gemm_f16<1,1><<<dim3(32, 8), blk, 0, stream>>>(trg_h, nullptr, nullptr, WtT, bt, tkey, 2048, HD);
  write_pad_f16<<<dim3(16*16*512/256), blk, 0, stream>>>(skey, bs, tkey, bt);

  attn_kernel<<<dim3(MQ/2), dim3(512), 0, stream>>>(q_h, skey, tkey, sctx, tctx);

  gemm_f16<3,2><<<dim3(64, 8), blk, 0, stream>>>(query_h, sctx, tctx, WoT, bo, out, MQ, HD);
}

// Round 5
// 310.676 us; speedup vs baseline: 1.2070x; 1.2070x over previous
//
#include <hip/hip_runtime.h>
#include <math.h>

// Problem constants (fixed by the reference)
#define HD 512          // Q_DIM = F_DIM = H_DIM = OUT_DIM = 512
#define SP 129          // S+1 = T+1
#define RPAD 144        // padded key rows per batch (129 used, rest zero; 9x16)
#define NBATCH 16
#define MQ 4096         // 16*256 query rows
#define SCALE 0.04419417382415922f  // 1/sqrt(512)

typedef _Float16 f16;
typedef _Float16 f16x8 __attribute__((ext_vector_type(8)));
typedef _Float16 f16x4 __attribute__((ext_vector_type(4)));
typedef _Float16 f16x2 __attribute__((ext_vector_type(2)));
typedef float f32x4  __attribute__((ext_vector_type(4)));

__device__ __forceinline__ void gload_lds16(const f16* g, f16* l) {
  __builtin_amdgcn_global_load_lds(
      (const __attribute__((address_space(1))) void*)g,
      (__attribute__((address_space(3))) void*)l, 16, 0, 0);
}

// ---------------------------------------------------------------------------
// flat f32 -> f16 convert (8 elems/thread)
// ---------------------------------------------------------------------------
__global__ __launch_bounds__(256) void conv_f32_f16(
    const float* __restrict__ a, f16* __restrict__ o, int n)
{
  int base = (blockIdx.x * 256 + threadIdx.x) * 8;
  if (base < n) {
    float4 x = *(const float4*)(a + base);
    float4 y = *(const float4*)(a + base + 4);
    f16x8 v = { (f16)x.x, (f16)x.y, (f16)x.z, (f16)x.w,
                (f16)y.x, (f16)y.y, (f16)y.z, (f16)y.w };
    *(f16x8*)(o + base) = v;
  }
}

// ---------------------------------------------------------------------------
// W[K][N] f32 -> WT[N][K] f16 (transpose + convert), 64x64 LDS tiles
// ---------------------------------------------------------------------------
__global__ __launch_bounds__(256) void convT_f32_f16(
    const float* __restrict__ W, f16* __restrict__ WT, int K, int N)
{
  __shared__ float t[64][65];
  const int k0 = blockIdx.x * 64, n0 = blockIdx.y * 64;
  const int tid = threadIdx.x;
  const int r = tid >> 4, c4 = (tid & 15) * 4;
  #pragma unroll
  for (int i = 0; i < 4; ++i) {
    int k = r + 16*i;
    float4 v = *(const float4*)(W + (size_t)(k0 + k)*N + n0 + c4);
    t[k][c4] = v.x; t[k][c4+1] = v.y; t[k][c4+2] = v.z; t[k][c4+3] = v.w;
  }
  __syncthreads();
  #pragma unroll
  for (int i = 0; i < 4; ++i) {
    int n = r + 16*i;
    f16x4 v = { (f16)t[c4][n], (f16)t[c4+1][n], (f16)t[c4+2][n], (f16)t[c4+3][n] };
    *(f16x4*)(WT + (size_t)(n0 + n)*K + k0 + c4) = v;
  }
}

// ---------------------------------------------------------------------------
// f16 MFMA GEMM: C[M,N] = concat_seg(A)[M, NSEG*512] @ WT^T + bias
// MODE 0: f16 out; MODE 1: f16 out + key row remap (128/batch -> 144/batch);
// MODE 2: f32 out with tanh.
// ---------------------------------------------------------------------------
template<int NSEG, int MODE>
__global__ __launch_bounds__(256) void gemm_f16(
    const f16* __restrict__ A0, const f16* __restrict__ A1,
    const f16* __restrict__ A2, const f16* __restrict__ WT,
    const float* __restrict__ bias, void* __restrict__ Cv, int M, int N)
{
  __shared__ __align__(16) f16 As[64*64];
  __shared__ __align__(16) f16 Bs[64*64];
  const int KTOT = NSEG * 512;
  const int tid  = threadIdx.x;
  const int lane = tid & 63;
  const int w    = tid >> 6;
  const int wr   = w & 1, wc = w >> 1;
  const int fq   = lane >> 4, fr = lane & 15;
  const int bm = blockIdx.x * 64, bn = blockIdx.y * 64;

  f32x4 acc[2][2] = {};

  for (int k0 = 0; k0 < KTOT; k0 += 64) {
    const int seg  = k0 >> 9;
    const f16* Ap  = (NSEG == 1) ? A0 : (seg == 0 ? A0 : (seg == 1 ? A1 : A2));
    const int kloc = k0 & 511;
    #pragma unroll
    for (int i = 0; i < 2; ++i) {
      int idx = tid + 256*i;
      int r = idx >> 3, c = idx & 7;
      const uint4 va = *(const uint4*)(Ap + (size_t)(bm + r)*512 + kloc + c*8);
      const uint4 vb = *(const uint4*)(WT + (size_t)(bn + r)*KTOT + k0 + c*8);
      int o = ((r << 7) + (c << 4)) ^ ((r & 7) << 4);
      *(uint4*)((char*)As + o) = va;
      *(uint4*)((char*)Bs + o) = vb;
    }
    __syncthreads();
    #pragma unroll
    for (int ks = 0; ks < 2; ++ks) {
      f16x8 af[2], bf_[2];
      #pragma unroll
      for (int i = 0; i < 2; ++i) {
        int ra = wr*32 + i*16 + fr;
        int oa = ((ra << 7) + (ks << 6) + (fq << 4)) ^ ((ra & 7) << 4);
        af[i] = *(const f16x8*)((const char*)As + oa);
        int rb = wc*32 + i*16 + fr;
        int ob = ((rb << 7) + (ks << 6) + (fq << 4)) ^ ((rb & 7) << 4);
        bf_[i] = *(const f16x8*)((const char*)Bs + ob);
      }
      #pragma unroll
      for (int i = 0; i < 2; ++i)
        #pragma unroll
        for (int j = 0; j < 2; ++j)
          acc[i][j] = __builtin_amdgcn_mfma_f32_16x16x32_f16(af[i], bf_[j], acc[i][j], 0, 0, 0);
    }
    __syncthreads();
  }

  #pragma unroll
  for (int i = 0; i < 2; ++i) {
    #pragma unroll
    for (int j = 0; j < 2; ++j) {
      int n = bn + wc*32 + j*16 + fr;
      float bv = bias[n];
      #pragma unroll
      for (int r = 0; r < 4; ++r) {
        int m = bm + wr*32 + i*16 + fq*4 + r;
        float x = acc[i][j][r] + bv;
        if (MODE == 0) {
          ((f16*)Cv)[(size_t)m*N + n] = (f16)x;
        } else if (MODE == 1) {
          int mo = (m >> 7) * RPAD + (m & 127);
          ((f16*)Cv)[(size_t)mo*N + n] = (f16)x;
        } else {
          x = fminf(fmaxf(x, -20.f), 20.f);
          float e = __expf(2.0f * x);
          ((float*)Cv)[(size_t)m*N + n] = (e - 1.0f) / (e + 1.0f);
        }
      }
    }
  }
}

// Rows 128..143 of each batch: row 128 = bias (reference pad row), rest 0.
__global__ void write_pad_f16(f16* __restrict__ skey, const float* __restrict__ bs,
                              f16* __restrict__ tkey, const float* __restrict__ bt)
{
  int i = blockIdx.x * 256 + threadIdx.x;   // 16 batches * 16 rows * 512
  int b = i >> 13;
  int r = 128 + ((i >> 9) & 15);
  int k = i & 511;
  size_t off = ((size_t)b*RPAD + r)*HD + k;
  skey[off] = (r == 128) ? (f16)bs[k] : (f16)0.f;
  tkey[off] = (r == 128) ? (f16)bt[k] : (f16)0.f;
}

// ---------------------------------------------------------------------------
// Fused trilinear attention, f16 MFMA. 256 threads / 4 waves; 2 query rows
// per block, BOTH computed by every wave (shared LDS reads: raw s_key frag is
// scaled by q0 and q1 -> 2x MFMA per ds_read). 5x5 overlap quadrants as r3.
// Staging via global_load_lds into a K=32 double buffer, layout [c][192 rows]
// (conflict-free ds_read_b128, linear dest). Counted vmcnt(6) pipelining.
// P never materialized: only gmax, row sums ws, col sums wt.
// ---------------------------------------------------------------------------
__global__ __launch_bounds__(256, 2) void attn_kernel(
    const f16* __restrict__ qg,      // (4096, 512)
    const f16* __restrict__ s_key,   // (16, 144, 512)
    const f16* __restrict__ t_key,   // (16, 144, 512)
    f16* __restrict__ s_ctx,         // (4096, 512)
    f16* __restrict__ t_ctx)         // (4096, 512)
{
  // [buf][key][c][192 rows] ; f16 index = ((buf*2+key)*4+c)*1536 + row*8
  __shared__ __align__(16) f16 KB[2*2*4*1536];   // 49152 B
  __shared__ __align__(16) f16 qs[2][HD];
  __shared__ float wsum[2][2][2][RPAD];  // [ws|wt][qrow][half][s]
  __shared__ float red[8];

  const int tid  = threadIdx.x;
  const int lane = tid & 63;
  const int w    = tid >> 6;
  const int rb   = w & 1;    // tile-row half: tiles {0..4} / {4..8} (overlap 4)
  const int cb   = w >> 1;   // tile-col half
  const int fq   = lane >> 4;
  const int fr   = lane & 15;

  // XCD-chunked swizzle: 2048 blocks -> 256 consecutive pairs per XCD
  const int pair = ((int)blockIdx.x & 7) * 256 + ((int)blockIdx.x >> 3);
  const int gid0 = pair * 2;
  const int b    = gid0 >> 8;
  const f16* skg = s_key + (size_t)b * RPAD * HD;
  const f16* tkg = t_key + (size_t)b * RPAD * HD;

  // both query rows into LDS
  if (tid < 128) {
    int row = tid >> 6, n = tid & 63;
    *(uint4*)(&qs[row][n*8]) = *(const uint4*)(qg + (size_t)(gid0 + row)*HD + n*8);
  }

  // stage one K=32 tile of both keys into buf (24 wave-insts; 6 per wave)
  auto stage = [&](int kt, int buf) {
    #pragma unroll
    for (int n = 0; n < 6; ++n) {
      int idx = w + 4*n;               // 0..23
      int key = idx >= 12;
      int wi  = idx - key*12;          // 0..11
      int c   = wi / 3;                // k-chunk 0..3
      int r3  = wi - c*3;              // 64-row block 0..2
      const f16* g = (key ? tkg : skg)
                   + (size_t)(r3*64 + lane)*HD + kt*32 + c*8;
      f16* l = &KB[((buf*2 + key)*4 + c)*1536 + r3*512];
      gload_lds16(g, l);
    }
  };

  f32x4 acc0[5][5] = {};
  f32x4 acc1[5][5] = {};

  auto mfma_kt = [&](int kt, int cur) {
    const f16x8 qv0 = *(const f16x8*)(&qs[0][kt*32 + fq*8]);
    const f16x8 qv1 = *(const f16x8*)(&qs[1][kt*32 + fq*8]);
    const int abase = ((cur*2 + 0)*4 + fq) * 1536;
    const int bbase = ((cur*2 + 1)*4 + fq) * 1536;
    f16x8 B[5];
    #pragma unroll
    for (int j = 0; j < 5; ++j) {
      int rt = 16*(cb*4 + j) + fr;
      B[j] = *(const f16x8*)(&KB[bbase + rt*8]);
    }
    __builtin_amdgcn_s_setprio(1);
    #pragma unroll
    for (int i = 0; i < 5; ++i) {
      int rs = 16*(rb*4 + i) + fr;
      f16x8 raw = *(const f16x8*)(&KB[abase + rs*8]);
      f16x8 a0 = raw * qv0;            // v_pk_mul_f16
      f16x8 a1 = raw * qv1;
      #pragma unroll
      for (int j = 0; j < 5; ++j) {
        acc0[i][j] = __builtin_amdgcn_mfma_f32_16x16x32_f16(a0, B[j], acc0[i][j], 0, 0, 0);
        acc1[i][j] = __builtin_amdgcn_mfma_f32_16x16x32_f16(a1, B[j], acc1[i][j], 0, 0, 0);
      }
    }
    __builtin_amdgcn_s_setprio(0);
  };

  stage(0, 0);
  __syncthreads();                      // drains vmcnt(0); qs visible

  for (int kt = 0; kt < 16; ++kt) {
    const int cur = kt & 1;
    if (kt < 15) {
      stage(kt + 1, cur ^ 1);
      asm volatile("s_waitcnt vmcnt(6)" ::: "memory");   // old 6 landed
    } else {
      asm volatile("s_waitcnt vmcnt(0)" ::: "memory");
    }
    __builtin_amdgcn_s_barrier();       // buf[cur] fully staged for all waves
    mfma_kt(kt, cur);
    __builtin_amdgcn_s_barrier();       // reads done before next overwrite
  }

  // ---- masked max over valid (s<=128, t<=128), both rows ----
  float m0 = -3e38f, m1 = -3e38f;
  #pragma unroll
  for (int i = 0; i < 5; ++i) {
    #pragma unroll
    for (int j = 0; j < 5; ++j) {
      #pragma unroll
      for (int r = 0; r < 4; ++r) {
        int srow = 16*(rb*4 + i) + fq*4 + r;
        int tcol = 16*(cb*4 + j) + fr;
        bool ok = (srow <= 128) && (tcol <= 128);
        m0 = ok ? fmaxf(m0, acc0[i][j][r]) : m0;
        m1 = ok ? fmaxf(m1, acc1[i][j][r]) : m1;
      }
    }
  }
  #pragma unroll
  for (int off = 32; off > 0; off >>= 1) {
    m0 = fmaxf(m0, __shfl_xor(m0, off));
    m1 = fmaxf(m1, __shfl_xor(m1, off));
  }
  if (lane == 0) { red[w] = m0; red[4 + w] = m1; }
  __syncthreads();
  const float g0 = fmaxf(fmaxf(red[0], red[1]), fmaxf(red[2], red[3])) * SCALE;
  const float g1 = fmaxf(fmaxf(red[4], red[5]), fmaxf(red[6], red[7])) * SCALE;

  // ---- exp in registers (invalid -> 0) ----
  #pragma unroll
  for (int i = 0; i < 5; ++i) {
    #pragma unroll
    for (int j = 0; j < 5; ++j) {
      #pragma unroll
      for (int r = 0; r < 4; ++r) {
        int srow = 16*(rb*4 + i) + fq*4 + r;
        int tcol = 16*(cb*4 + j) + fr;
        bool ok = (srow <= 128) && (tcol <= 128);
        float p0 = __expf(acc0[i][j][r] * SCALE - g0);
        float p1 = __expf(acc1[i][j][r] * SCALE - g1);
        acc0[i][j][r] = ok ? p0 : 0.0f;
        acc1[i][j][r] = ok ? p1 : 0.0f;
      }
    }
  }

  // ---- ws: row sums (dedup overlapped tile 4) ----
  #pragma unroll
  for (int i = 0; i < 5; ++i) {
    if (!(rb == 1 && i == 0)) {
      #pragma unroll
      for (int r = 0; r < 4; ++r) {
        float rs0 = 0.f, rs1 = 0.f;
        #pragma unroll
        for (int j = 0; j < 5; ++j)
          if (!(cb == 1 && j == 0)) { rs0 += acc0[i][j][r]; rs1 += acc1[i][j][r]; }
        rs0 += __shfl_xor(rs0, 1); rs0 += __shfl_xor(rs0, 2);
        rs0 += __shfl_xor(rs0, 4); rs0 += __shfl_xor(rs0, 8);
        rs1 += __shfl_xor(rs1, 1); rs1 += __shfl_xor(rs1, 2);
        rs1 += __shfl_xor(rs1, 4); rs1 += __shfl_xor(rs1, 8);
        if (fr == 0) {
          int s = 16*(rb*4 + i) + fq*4 + r;
          wsum[0][0][cb][s] = rs0;
          wsum[0][1][cb][s] = rs1;
        }
      }
    }
  }
  // ---- wt: col sums ----
  #pragma unroll
  for (int j = 0; j < 5; ++j) {
    if (!(cb == 1 && j == 0)) {
      float cs0 = 0.f, cs1 = 0.f;
      #pragma unroll
      for (int i = 0; i < 5; ++i)
        if (!(rb == 1 && i == 0)) {
          #pragma unroll
          for (int r = 0; r < 4; ++r) { cs0 += acc0[i][j][r]; cs1 += acc1[i][j][r]; }
        }
      cs0 += __shfl_xor(cs0, 16); cs0 += __shfl_xor(cs0, 32);
      cs1 += __shfl_xor(cs1, 16); cs1 += __shfl_xor(cs1, 32);
      if (lane < 16) {
        int t = 16*(cb*4 + j) + fr;
        wsum[1][0][rb][t] = cs0;
        wsum[1][1][rb][t] = cs1;
      }
    }
  }
  __syncthreads();

  // ---- Z per query row ----
  float z0 = 0.f, z1 = 0.f;
  if (tid < RPAD) {
    z0 = wsum[0][0][0][tid] + wsum[0][0][1][tid];
    z1 = wsum[0][1][0][tid] + wsum[0][1][1][tid];
  }
  #pragma unroll
  for (int off = 32; off > 0; off >>= 1) {
    z0 += __shfl_xor(z0, off);
    z1 += __shfl_xor(z1, off);
  }
  if (lane == 0) { red[w] = z0; red[4 + w] = z1; }
  __syncthreads();
  const float iz0 = 1.0f / (red[0] + red[1] + red[2] + red[3]);
  const float iz1 = 1.0f / (red[4] + red[5] + red[6] + red[7]);

  // ---- contexts: thread = (key-type, 4 k-slots), both query rows ----
  {
    const int ksel = tid >> 7;            // 0: s_ctx, 1: t_ctx
    const int k4 = (tid & 127) * 4;
    const f16* kg = ksel ? tkg : skg;
    float a00 = 0.f, a01 = 0.f, a02 = 0.f, a03 = 0.f;
    float a10 = 0.f, a11 = 0.f, a12 = 0.f, a13 = 0.f;
    for (int s = 0; s < SP; ++s) {
      float w0 = wsum[ksel][0][0][s] + wsum[ksel][0][1][s];
      float w1 = wsum[ksel][1][0][s] + wsum[ksel][1][1][s];
      f16x4 kv = *(const f16x4*)(kg + (size_t)s*HD + k4);
      float k0f = (float)kv[0], k1f = (float)kv[1], k2f = (float)kv[2], k3f = (float)kv[3];
      a00 = fmaf(w0, k0f, a00); a01 = fmaf(w0, k1f, a01);
      a02 = fmaf(w0, k2f, a02); a03 = fmaf(w0, k3f, a03);
      a10 = fmaf(w1, k0f, a10); a11 = fmaf(w1, k1f, a11);
      a12 = fmaf(w1, k2f, a12); a13 = fmaf(w1, k3f, a13);
    }
    f16* dst = ksel ? t_ctx : s_ctx;
    f16x4 o0 = { (f16)(a00*iz0), (f16)(a01*iz0), (f16)(a02*iz0), (f16)(a03*iz0) };
    f16x4 o1 = { (f16)(a10*iz1), (f16)(a11*iz1), (f16)(a12*iz1), (f16)(a13*iz1) };
    *(f16x4*)(dst + (size_t)gid0*HD + k4) = o0;
    *(f16x4*)(dst + (size_t)(gid0 + 1)*HD + k4) = o1;
  }
}

extern "C" void kernel_launch(void* const* d_in, const int* in_sizes, int n_in,
                              void* d_out, int out_size, void* d_ws, size_t ws_size,
                              hipStream_t stream) {
  (void)in_sizes; (void)n_in; (void)out_size; (void)ws_size;
  const float* query = (const float*)d_in[0];
  const float* src   = (const float*)d_in[1];
  const float* trg   = (const float*)d_in[2];
  const float* Wq    = (const float*)d_in[3];
  const float* bq    = (const float*)d_in[4];
  const float* Wsm   = (const float*)d_in[5];
  const float* bs    = (const float*)d_in[6];
  const float* Wtm   = (const float*)d_in[7];
  const float* bt    = (const float*)d_in[8];
  const float* Wo    = (const float*)d_in[9];
  const float* bo    = (const float*)d_in[10];
  float* out = (float*)d_out;

  // workspace layout (f16 buffers). NOTE: skey/tkey are followed by more
  // buffers — attn staging reads up to 48 rows past each batch (harmless).
  char* p = (char*)d_ws;
  f16* query_h = (f16*)p;                 p += (size_t)MQ*HD*2;
  f16* src_h   = (f16*)p;                 p += (size_t)2048*HD*2;
  f16* trg_h   = (f16*)p;                 p += (size_t)2048*HD*2;
  f16* WqT     = (f16*)p;                 p += (size_t)HD*HD*2;
  f16* WsT     = (f16*)p;                 p += (size_t)HD*HD*2;
  f16* WtT     = (f16*)p;                 p += (size_t)HD*HD*2;
  f16* WoT     = (f16*)p;                 p += (size_t)1536*HD*2;
  f16* q_h     = (f16*)p;                 p += (size_t)MQ*HD*2;
  f16* skey    = (f16*)p;                 p += (size_t)NBATCH*RPAD*HD*2;
  f16* tkey    = (f16*)p;                 p += (size_t)NBATCH*RPAD*HD*2;
  f16* sctx    = (f16*)p;                 p += (size_t)MQ*HD*2;
  f16* tctx    = (f16*)p;                 p += (size_t)MQ*HD*2;

  dim3 blk(256);
  conv_f32_f16<<<dim3(MQ*HD/8/256), blk, 0, stream>>>(query, query_h, MQ*HD);
  conv_f32_f16<<<dim3(2048*HD/8/256), blk, 0, stream>>>(src, src_h, 2048*HD);
  conv_f32_f16<<<dim3(2048*HD/8/256), blk, 0, stream>>>(trg, trg_h, 2048*HD);
  convT_f32_f16<<<dim3(8, 8), blk, 0, stream>>>(Wq, WqT, HD, HD);
  convT_f32_f16<<<dim3(8, 8), blk, 0, stream>>>(Wsm, WsT, HD, HD);
  convT_f32_f16<<<dim3(8, 8), blk, 0, stream>>>(Wtm, WtT, HD, HD);
  convT_f32_f16<<<dim3(24, 8), blk, 0, stream>>>(Wo, WoT, 1536, HD);

  gemm_f16<1,0><<<dim3(64, 8), blk, 0, stream>>>(query_h, nullptr, nullptr, WqT, bq, q_h, MQ, HD);
  gemm_f16<1,1><<<dim3(32, 8), blk, 0, stream>>>(src_h, nullptr, nullptr, WsT, bs, skey, 2048, HD);
  gemm_f16<1,1><<<dim3(32, 8), blk, 0, stream>>>(trg_h, nullptr, nullptr, WtT, bt, tkey, 2048, HD);
  write_pad_f16<<<dim3(16*16*512/256), blk, 0, stream>>>(skey, bs, tkey, bt);

  attn_kernel<<<dim3(MQ/2), dim3(256), 0, stream>>>(q_h, skey, tkey, sctx, tctx);

  gemm_f16<3,2><<<dim3(64, 8), blk, 0, stream>>>(query_h, sctx, tctx, WoT, bo, out, MQ, HD);
}

// Round 6
// 199.726 us; speedup vs baseline: 1.8776x; 1.5555x over previous
//
#include <hip/hip_runtime.h>
#include <math.h>

// Problem constants (fixed by the reference)
#define HD 512          // Q_DIM = F_DIM = H_DIM = OUT_DIM = 512
#define SP 129          // S+1 = T+1
#define RPAD 144        // padded key rows per batch (129 used, rest zero; 9x16)
#define WPAD 160        // padded weight-vector length (129 used, rest zero)
#define NBATCH 16
#define MQ 4096         // 16*256 query rows
#define SCALE 0.04419417382415922f  // 1/sqrt(512)

typedef _Float16 f16;
typedef _Float16 f16x8 __attribute__((ext_vector_type(8)));
typedef _Float16 f16x4 __attribute__((ext_vector_type(4)));
typedef float f32x4  __attribute__((ext_vector_type(4)));

__device__ __forceinline__ void gload_lds16(const f16* g, f16* l) {
  __builtin_amdgcn_global_load_lds(
      (const __attribute__((address_space(1))) void*)g,
      (__attribute__((address_space(3))) void*)l, 16, 0, 0);
}

// ---------------------------------------------------------------------------
// flat f32 -> f16 convert (8 elems/thread)
// ---------------------------------------------------------------------------
__global__ __launch_bounds__(256) void conv_f32_f16(
    const float* __restrict__ a, f16* __restrict__ o, int n)
{
  int base = (blockIdx.x * 256 + threadIdx.x) * 8;
  if (base < n) {
    float4 x = *(const float4*)(a + base);
    float4 y = *(const float4*)(a + base + 4);
    f16x8 v = { (f16)x.x, (f16)x.y, (f16)x.z, (f16)x.w,
                (f16)y.x, (f16)y.y, (f16)y.z, (f16)y.w };
    *(f16x8*)(o + base) = v;
  }
}

// ---------------------------------------------------------------------------
// W[K][N] f32 -> WT[N][K] f16 (transpose + convert), 64x64 LDS tiles
// ---------------------------------------------------------------------------
__global__ __launch_bounds__(256) void convT_f32_f16(
    const float* __restrict__ W, f16* __restrict__ WT, int K, int N)
{
  __shared__ float t[64][65];
  const int k0 = blockIdx.x * 64, n0 = blockIdx.y * 64;
  const int tid = threadIdx.x;
  const int r = tid >> 4, c4 = (tid & 15) * 4;
  #pragma unroll
  for (int i = 0; i < 4; ++i) {
    int k = r + 16*i;
    float4 v = *(const float4*)(W + (size_t)(k0 + k)*N + n0 + c4);
    t[k][c4] = v.x; t[k][c4+1] = v.y; t[k][c4+2] = v.z; t[k][c4+3] = v.w;
  }
  __syncthreads();
  #pragma unroll
  for (int i = 0; i < 4; ++i) {
    int n = r + 16*i;
    f16x4 v = { (f16)t[c4][n], (f16)t[c4+1][n], (f16)t[c4+2][n], (f16)t[c4+3][n] };
    *(f16x4*)(WT + (size_t)(n0 + n)*K + k0 + c4) = v;
  }
}

// ---------------------------------------------------------------------------
// f16 MFMA GEMM: C[M,N] = concat_seg(A)[M, NSEG*512] @ WT^T + bias
// MODE 0: f16 out; MODE 2: f32 out with tanh;
// MODE 3: f16 out + key row remap (128/batch -> 144/batch) + transposed copy
//         CT[b][n][mb] (stride WPAD) for the ctx GEMM.
// ---------------------------------------------------------------------------
template<int NSEG, int MODE>
__global__ __launch_bounds__(256) void gemm_f16(
    const f16* __restrict__ A0, const f16* __restrict__ A1,
    const f16* __restrict__ A2, const f16* __restrict__ WT,
    const float* __restrict__ bias, void* __restrict__ Cv,
    f16* __restrict__ CT, int M, int N)
{
  __shared__ __align__(16) f16 As[64*64];
  __shared__ __align__(16) f16 Bs[64*64];
  const int KTOT = NSEG * 512;
  const int tid  = threadIdx.x;
  const int lane = tid & 63;
  const int w    = tid >> 6;
  const int wr   = w & 1, wc = w >> 1;
  const int fq   = lane >> 4, fr = lane & 15;
  const int bm = blockIdx.x * 64, bn = blockIdx.y * 64;

  f32x4 acc[2][2] = {};

  for (int k0 = 0; k0 < KTOT; k0 += 64) {
    const int seg  = k0 >> 9;
    const f16* Ap  = (NSEG == 1) ? A0 : (seg == 0 ? A0 : (seg == 1 ? A1 : A2));
    const int kloc = k0 & 511;
    #pragma unroll
    for (int i = 0; i < 2; ++i) {
      int idx = tid + 256*i;
      int r = idx >> 3, c = idx & 7;
      const uint4 va = *(const uint4*)(Ap + (size_t)(bm + r)*512 + kloc + c*8);
      const uint4 vb = *(const uint4*)(WT + (size_t)(bn + r)*KTOT + k0 + c*8);
      int o = ((r << 7) + (c << 4)) ^ ((r & 7) << 4);
      *(uint4*)((char*)As + o) = va;
      *(uint4*)((char*)Bs + o) = vb;
    }
    __syncthreads();
    #pragma unroll
    for (int ks = 0; ks < 2; ++ks) {
      f16x8 af[2], bf_[2];
      #pragma unroll
      for (int i = 0; i < 2; ++i) {
        int ra = wr*32 + i*16 + fr;
        int oa = ((ra << 7) + (ks << 6) + (fq << 4)) ^ ((ra & 7) << 4);
        af[i] = *(const f16x8*)((const char*)As + oa);
        int rb = wc*32 + i*16 + fr;
        int ob = ((rb << 7) + (ks << 6) + (fq << 4)) ^ ((rb & 7) << 4);
        bf_[i] = *(const f16x8*)((const char*)Bs + ob);
      }
      #pragma unroll
      for (int i = 0; i < 2; ++i)
        #pragma unroll
        for (int j = 0; j < 2; ++j)
          acc[i][j] = __builtin_amdgcn_mfma_f32_16x16x32_f16(af[i], bf_[j], acc[i][j], 0, 0, 0);
    }
    __syncthreads();
  }

  #pragma unroll
  for (int i = 0; i < 2; ++i) {
    #pragma unroll
    for (int j = 0; j < 2; ++j) {
      int n = bn + wc*32 + j*16 + fr;
      float bv = bias[n];
      if (MODE == 3) {
        const int m0 = bm + wr*32 + i*16 + fq*4;
        f16 vals[4];
        #pragma unroll
        for (int r = 0; r < 4; ++r) {
          int m = m0 + r;
          f16 x = (f16)(acc[i][j][r] + bv);
          vals[r] = x;
          int mo = (m >> 7) * RPAD + (m & 127);
          ((f16*)Cv)[(size_t)mo*N + n] = x;
        }
        f16x4 v4 = { vals[0], vals[1], vals[2], vals[3] };
        *(f16x4*)(CT + ((size_t)(m0 >> 7)*512 + n)*WPAD + (m0 & 127)) = v4;
      } else {
        #pragma unroll
        for (int r = 0; r < 4; ++r) {
          int m = bm + wr*32 + i*16 + fq*4 + r;
          float x = acc[i][j][r] + bv;
          if (MODE == 0) {
            ((f16*)Cv)[(size_t)m*N + n] = (f16)x;
          } else {
            x = fminf(fmaxf(x, -20.f), 20.f);
            float e = __expf(2.0f * x);
            ((float*)Cv)[(size_t)m*N + n] = (e - 1.0f) / (e + 1.0f);
          }
        }
      }
    }
  }
}

// Pad fills: key rows 128..143 (row 128 = bias = reference pad row, rest 0)
// and keyT cols 128..159 per (batch, n).
__global__ void write_pad_f16(f16* __restrict__ skey, const float* __restrict__ bs,
                              f16* __restrict__ tkey, const float* __restrict__ bt,
                              f16* __restrict__ skeyT, f16* __restrict__ tkeyT)
{
  int i = blockIdx.x * 256 + threadIdx.x;   // 16*512
  int b = i >> 9, n = i & 511;
  for (int r = 128; r < RPAD; ++r) {
    skey[((size_t)b*RPAD + r)*HD + n] = (r == 128) ? (f16)bs[n] : (f16)0.f;
    tkey[((size_t)b*RPAD + r)*HD + n] = (r == 128) ? (f16)bt[n] : (f16)0.f;
  }
  size_t o = ((size_t)b*512 + n)*WPAD;
  for (int c = 128; c < WPAD; ++c) {
    skeyT[o + c] = (c == 128) ? (f16)bs[n] : (f16)0.f;
    tkeyT[o + c] = (c == 128) ? (f16)bt[n] : (f16)0.f;
  }
}

// ---------------------------------------------------------------------------
// Border scores (raw, f32): Sb[0][l][t] = sum_k q[l,k]*sk128[k]*tk[t,k]
//                           Sb[1][l][s] = sum_k q[l,k]*tk128[k]*sk[s,k]
// grid 128 blocks: b(16) x z(2) x mt(4); block = 64 l-rows x 144 cols.
// ---------------------------------------------------------------------------
__global__ __launch_bounds__(256) void border_kernel(
    const f16* __restrict__ q_h, const f16* __restrict__ skey,
    const f16* __restrict__ tkey, float* __restrict__ Sb)
{
  const int blk = blockIdx.x;
  const int b = blk >> 3, z = (blk >> 2) & 1, mt = blk & 3;
  const f16* keys = (z ? skey : tkey) + (size_t)b*RPAD*HD;
  const f16* u    = (z ? tkey : skey) + ((size_t)b*RPAD + 128)*HD;
  const int gid0 = b*256 + mt*64;

  __shared__ __align__(16) f16 Ks[RPAD*32];
  const int tid = threadIdx.x, lane = tid & 63, w = tid >> 6;
  const int fq = lane >> 4, fr = lane & 15;

  f32x4 acc[9] = {};

  for (int kt = 0; kt < 16; ++kt) {
    uint4 t0, t1, t2;
    {
      int r0 = tid >> 2, c0 = tid & 3;
      t0 = *(const uint4*)(keys + (size_t)r0*HD + kt*32 + c0*8);
      int r1 = (tid + 256) >> 2, c1 = tid & 3;
      t1 = *(const uint4*)(keys + (size_t)r1*HD + kt*32 + c1*8);
      if (tid < 64) {
        int r2 = (tid + 512) >> 2, c2 = tid & 3;
        t2 = *(const uint4*)(keys + (size_t)r2*HD + kt*32 + c2*8);
      }
    }
    __syncthreads();
    {
      int r0 = tid >> 2, c0 = tid & 3;
      *(uint4*)(&Ks[r0*32 + c0*8]) = t0;
      int r1 = (tid + 256) >> 2;
      *(uint4*)(&Ks[r1*32 + c0*8]) = t1;
      if (tid < 64) {
        int r2 = (tid + 512) >> 2;
        *(uint4*)(&Ks[r2*32 + c0*8]) = t2;
      }
    }
    __syncthreads();
    const f16x8 qf = *(const f16x8*)(q_h + (size_t)(gid0 + w*16 + fr)*HD + kt*32 + fq*8);
    const f16x8 uv = *(const f16x8*)(u + kt*32 + fq*8);
    const f16x8 a = qf * uv;
    #pragma unroll
    for (int j = 0; j < 9; ++j) {
      const f16x8 bfr = *(const f16x8*)(&Ks[(j*16 + fr)*32 + fq*8]);
      acc[j] = __builtin_amdgcn_mfma_f32_16x16x32_f16(a, bfr, acc[j], 0, 0, 0);
    }
  }

  float* dst = Sb + (size_t)z*MQ*RPAD;
  #pragma unroll
  for (int j = 0; j < 9; ++j)
    #pragma unroll
    for (int r = 0; r < 4; ++r)
      dst[(size_t)(gid0 + w*16 + fq*4 + r)*RPAD + j*16 + fr] = acc[j][r];
}

// ---------------------------------------------------------------------------
// Core trilinear attention: 1 query row / block, 4 waves, 128x128 core only
// (borders read from Sb). Outputs normalized weights wsn/wtn [4096][160] f16.
// Staging: global_load_lds (k-contiguous), K=32 dbuf, counted vmcnt(4).
// ---------------------------------------------------------------------------
__global__ __launch_bounds__(256, 4) void attn_core(
    const f16* __restrict__ qg,      // (4096, 512)
    const f16* __restrict__ skey,    // (16, 144, 512)
    const f16* __restrict__ tkey,    // (16, 144, 512)
    const float* __restrict__ Sb,    // (2, 4096, 144) raw border scores
    f16* __restrict__ wsn,           // (4096, 160) normalized row weights
    f16* __restrict__ wtn)           // (4096, 160) normalized col weights
{
  __shared__ __align__(16) f16 KB[2*2*128*32];   // [buf][key][row(128)][32] = 32 KB
  __shared__ __align__(16) f16 qs[HD];
  __shared__ float wsA[2][128];   // rowsum partial by col-half
  __shared__ float wtA[2][128];   // colsum partial by row-half
  __shared__ float redA[4], redB[4], redC[4], redD[4], redE[4];
  __shared__ float cornerP;

  const int tid  = threadIdx.x;
  const int lane = tid & 63;
  const int w    = tid >> 6;
  const int rb   = w & 1;    // row half (s tiles 0..3 / 4..7)
  const int cb   = w >> 1;   // col half
  const int fq   = lane >> 4;
  const int fr   = lane & 15;

  // XCD-chunked swizzle: 4096 blocks -> 512 consecutive rows per XCD
  const int gid = ((int)blockIdx.x & 7) * 512 + ((int)blockIdx.x >> 3);
  const int b   = gid >> 8;
  const f16* skg = skey + (size_t)b * RPAD * HD;
  const f16* tkg = tkey + (size_t)b * RPAD * HD;

  if (tid < 64) *(uint4*)(qs + tid*8) = *(const uint4*)(qg + (size_t)gid*HD + tid*8);

  // stage one K=32 tile of both keys (16 wave-insts; 4 per wave)
  auto stage = [&](int kt, int buf) {
    #pragma unroll
    for (int n = 0; n < 4; ++n) {
      int idx = w*4 + n;             // 0..15
      int key = idx >> 3;
      int rg  = idx & 7;             // 16-row group
      const f16* g = (key ? tkg : skg)
                   + (size_t)(rg*16 + (lane >> 2))*HD + kt*32 + (lane & 3)*8;
      f16* l = &KB[((buf*2 + key)*128 + rg*16)*32];
      gload_lds16(g, l);
    }
  };

  f32x4 acc[4][4] = {};

  auto mfma_kt = [&](int kt, int cur) {
    const f16x8 qv = *(const f16x8*)(&qs[kt*32 + fq*8]);
    const int abase = (cur*2 + 0)*128*32;
    const int bbase = (cur*2 + 1)*128*32;
    f16x8 B[4];
    #pragma unroll
    for (int j = 0; j < 4; ++j) {
      int rt = cb*64 + j*16 + fr;
      B[j] = *(const f16x8*)(&KB[bbase + rt*32 + fq*8]);
    }
    __builtin_amdgcn_s_setprio(1);
    #pragma unroll
    for (int i = 0; i < 4; ++i) {
      int rs = rb*64 + i*16 + fr;
      const f16x8 raw = *(const f16x8*)(&KB[abase + rs*32 + fq*8]);
      const f16x8 a = raw * qv;      // v_pk_mul_f16
      #pragma unroll
      for (int j = 0; j < 4; ++j)
        acc[i][j] = __builtin_amdgcn_mfma_f32_16x16x32_f16(a, B[j], acc[i][j], 0, 0, 0);
    }
    __builtin_amdgcn_s_setprio(0);
  };

  stage(0, 0);
  __syncthreads();                    // drains vmcnt(0); qs visible

  for (int kt = 0; kt < 16; ++kt) {
    const int cur = kt & 1;
    if (kt < 15) {
      stage(kt + 1, cur ^ 1);
      asm volatile("s_waitcnt vmcnt(4)" ::: "memory");   // prev tile landed
    } else {
      asm volatile("s_waitcnt vmcnt(0)" ::: "memory");
    }
    __builtin_amdgcn_s_barrier();
    mfma_kt(kt, cur);
    __builtin_amdgcn_s_barrier();
  }

  // ---- max: core (regs) + border (global) ----
  float m = -3e38f;
  #pragma unroll
  for (int i = 0; i < 4; ++i)
    #pragma unroll
    for (int j = 0; j < 4; ++j)
      #pragma unroll
      for (int r = 0; r < 4; ++r) m = fmaxf(m, acc[i][j][r]);
  #pragma unroll
  for (int off = 32; off > 0; off >>= 1) m = fmaxf(m, __shfl_xor(m, off));
  if (lane == 0) redA[w] = m;

  const float* SbT = Sb + (size_t)gid*RPAD;
  const float* SbS = Sb + (size_t)MQ*RPAD + (size_t)gid*RPAD;
  const float btv = (tid < 129) ? SbT[tid] : -3e38f;
  const float bsv = (tid < 128) ? SbS[tid] : -3e38f;
  float bm = fmaxf(btv, bsv);
  #pragma unroll
  for (int off = 32; off > 0; off >>= 1) bm = fmaxf(bm, __shfl_xor(bm, off));
  if (lane == 0) redB[w] = bm;
  __syncthreads();
  const float mraw = fmaxf(
      fmaxf(fmaxf(redA[0], redA[1]), fmaxf(redA[2], redA[3])),
      fmaxf(fmaxf(redB[0], redB[1]), fmaxf(redB[2], redB[3])));

  // ---- exp core + core sum ----
  float csum = 0.f;
  #pragma unroll
  for (int i = 0; i < 4; ++i)
    #pragma unroll
    for (int j = 0; j < 4; ++j)
      #pragma unroll
      for (int r = 0; r < 4; ++r) {
        float p = __expf((acc[i][j][r] - mraw) * SCALE);
        acc[i][j][r] = p;
        csum += p;
      }
  #pragma unroll
  for (int off = 32; off > 0; off >>= 1) csum += __shfl_xor(csum, off);
  if (lane == 0) redC[w] = csum;

  // ---- row sums (over this wave's 4 col-tiles) ----
  #pragma unroll
  for (int i = 0; i < 4; ++i) {
    #pragma unroll
    for (int r = 0; r < 4; ++r) {
      float rs = acc[i][0][r] + acc[i][1][r] + acc[i][2][r] + acc[i][3][r];
      rs += __shfl_xor(rs, 1); rs += __shfl_xor(rs, 2);
      rs += __shfl_xor(rs, 4); rs += __shfl_xor(rs, 8);
      if (fr == 0) wsA[cb][rb*64 + i*16 + fq*4 + r] = rs;
    }
  }
  // ---- col sums (over this wave's 4 row-tiles) ----
  #pragma unroll
  for (int j = 0; j < 4; ++j) {
    float cs = 0.f;
    #pragma unroll
    for (int i = 0; i < 4; ++i)
      #pragma unroll
      for (int r = 0; r < 4; ++r) cs += acc[i][j][r];
    cs += __shfl_xor(cs, 16); cs += __shfl_xor(cs, 32);
    if (fq == 0) wtA[rb][cb*64 + j*16 + fr] = cs;
  }

  // ---- border exps + sums ----
  const float pbt = (tid < 129) ? __expf((btv - mraw) * SCALE) : 0.f;
  const float pbs = (tid < 128) ? __expf((bsv - mraw) * SCALE) : 0.f;
  float sbt = pbt, sbs = pbs;
  #pragma unroll
  for (int off = 32; off > 0; off >>= 1) {
    sbt += __shfl_xor(sbt, off);
    sbs += __shfl_xor(sbs, off);
  }
  if (lane == 0) { redD[w] = sbt; redE[w] = sbs; }
  if (tid == 128) cornerP = pbt;
  __syncthreads();

  const float pbt_sum = redD[0] + redD[1] + redD[2] + redD[3];
  const float pbs_sum = redE[0] + redE[1] + redE[2] + redE[3];
  const float core_sum = redC[0] + redC[1] + redC[2] + redC[3];
  const float invZ = 1.0f / (core_sum + pbt_sum + pbs_sum);

  if (tid < WPAD) {
    float wsv = (tid < 128) ? (wsA[0][tid] + wsA[1][tid] + pbs)
              : (tid == 128) ? pbt_sum : 0.f;
    float wtv = (tid < 128) ? (wtA[0][tid] + wtA[1][tid] + pbt)
              : (tid == 128) ? (pbs_sum + cornerP) : 0.f;
    wsn[(size_t)gid*WPAD + tid] = (f16)(wsv * invZ);
    wtn[(size_t)gid*WPAD + tid] = (f16)(wtv * invZ);
  }
}

// ---------------------------------------------------------------------------
// ctx GEMM: sctx[l][hd] = sum_s wsn[l][s] * skey[s][hd]  (keyT pre-transposed)
// grid (32 = b*2+z, 4 mt, 8 nt); K = 160 staged whole; 64x64 tile.
// ---------------------------------------------------------------------------
__global__ __launch_bounds__(256) void ctx_gemm(
    const f16* __restrict__ wsn, const f16* __restrict__ wtn,
    const f16* __restrict__ skeyT, const f16* __restrict__ tkeyT,
    f16* __restrict__ sctx, f16* __restrict__ tctx)
{
  __shared__ __align__(16) f16 As[64*168];
  __shared__ __align__(16) f16 Bs[64*168];
  const int z = blockIdx.x & 1, b = blockIdx.x >> 1;
  const int mt = blockIdx.y, nt = blockIdx.z;
  const int tid = threadIdx.x, lane = tid & 63, w = tid >> 6;
  const int wr = w & 1, wc = w >> 1;
  const int fq = lane >> 4, fr = lane & 15;

  const f16* A  = (z ? wtn : wsn) + ((size_t)b*256 + mt*64)*WPAD;
  const f16* Bt = (z ? tkeyT : skeyT) + ((size_t)b*512 + nt*64)*WPAD;

  for (int t = tid; t < 1280; t += 256) {
    int r = t / 20, c = t % 20;
    *(uint4*)(&As[r*168 + c*8]) = *(const uint4*)(A + (size_t)r*WPAD + c*8);
    *(uint4*)(&Bs[r*168 + c*8]) = *(const uint4*)(Bt + (size_t)r*WPAD + c*8);
  }
  __syncthreads();

  f32x4 acc[2][2] = {};
  #pragma unroll
  for (int ks = 0; ks < 5; ++ks) {
    f16x8 af[2], bf_[2];
    #pragma unroll
    for (int i = 0; i < 2; ++i) {
      af[i]  = *(const f16x8*)(&As[(wr*32 + i*16 + fr)*168 + ks*32 + fq*8]);
      bf_[i] = *(const f16x8*)(&Bs[(wc*32 + i*16 + fr)*168 + ks*32 + fq*8]);
    }
    #pragma unroll
    for (int i = 0; i < 2; ++i)
      #pragma unroll
      for (int j = 0; j < 2; ++j)
        acc[i][j] = __builtin_amdgcn_mfma_f32_16x16x32_f16(af[i], bf_[j], acc[i][j], 0, 0, 0);
  }

  f16* out = z ? tctx : sctx;
  #pragma unroll
  for (int i = 0; i < 2; ++i)
    #pragma unroll
    for (int j = 0; j < 2; ++j) {
      int col = nt*64 + wc*32 + j*16 + fr;
      #pragma unroll
      for (int r = 0; r < 4; ++r) {
        int row = b*256 + mt*64 + wr*32 + i*16 + fq*4 + r;
        out[(size_t)row*HD + col] = (f16)acc[i][j][r];
      }
    }
}

extern "C" void kernel_launch(void* const* d_in, const int* in_sizes, int n_in,
                              void* d_out, int out_size, void* d_ws, size_t ws_size,
                              hipStream_t stream) {
  (void)in_sizes; (void)n_in; (void)out_size; (void)ws_size;
  const float* query = (const float*)d_in[0];
  const float* src   = (const float*)d_in[1];
  const float* trg   = (const float*)d_in[2];
  const float* Wq    = (const float*)d_in[3];
  const float* bq    = (const float*)d_in[4];
  const float* Wsm   = (const float*)d_in[5];
  const float* bs    = (const float*)d_in[6];
  const float* Wtm   = (const float*)d_in[7];
  const float* bt    = (const float*)d_in[8];
  const float* Wo    = (const float*)d_in[9];
  const float* bo    = (const float*)d_in[10];
  float* out = (float*)d_out;

  // workspace layout (bytes); Sb aliases [src_h .. src_h+4.5MB) which is dead
  // by the time border_kernel runs (src_h/trg_h/WqT consumed by earlier GEMMs).
  char* p = (char*)d_ws;
  f16* query_h = (f16*)p;                 p += (size_t)MQ*HD*2;          // 4 MB
  f16* src_h   = (f16*)p;                 p += (size_t)2048*HD*2;        // 2 MB
  f16* trg_h   = (f16*)p;                 p += (size_t)2048*HD*2;        // 2 MB
  f16* WqT     = (f16*)p;                 p += (size_t)HD*HD*2;          // 0.5
  f16* WsT     = (f16*)p;                 p += (size_t)HD*HD*2;
  f16* WtT     = (f16*)p;                 p += (size_t)HD*HD*2;
  f16* WoT     = (f16*)p;                 p += (size_t)1536*HD*2;        // 1.5
  f16* q_h     = (f16*)p;                 p += (size_t)MQ*HD*2;          // 4 MB
  f16* skey    = (f16*)p;                 p += (size_t)NBATCH*RPAD*HD*2; // 2.36
  f16* tkey    = (f16*)p;                 p += (size_t)NBATCH*RPAD*HD*2;
  f16* skeyT   = (f16*)p;                 p += (size_t)NBATCH*HD*WPAD*2; // 2.62
  f16* tkeyT   = (f16*)p;                 p += (size_t)NBATCH*HD*WPAD*2;
  f16* wsn     = (f16*)p;                 p += (size_t)MQ*WPAD*2;        // 1.31
  f16* wtn     = (f16*)p;                 p += (size_t)MQ*WPAD*2;
  f16* sctx    = (f16*)p;                 p += (size_t)MQ*HD*2;          // 4 MB
  f16* tctx    = (f16*)p;                 p += (size_t)MQ*HD*2;
  float* Sb    = (float*)src_h;   // 2*4096*144*4 = 4.5 MB alias

  dim3 blk(256);
  conv_f32_f16<<<dim3(MQ*HD/8/256), blk, 0, stream>>>(query, query_h, MQ*HD);
  conv_f32_f16<<<dim3(2048*HD/8/256), blk, 0, stream>>>(src, src_h, 2048*HD);
  conv_f32_f16<<<dim3(2048*HD/8/256), blk, 0, stream>>>(trg, trg_h, 2048*HD);
  convT_f32_f16<<<dim3(8, 8), blk, 0, stream>>>(Wq, WqT, HD, HD);
  convT_f32_f16<<<dim3(8, 8), blk, 0, stream>>>(Wsm, WsT, HD, HD);
  convT_f32_f16<<<dim3(8, 8), blk, 0, stream>>>(Wtm, WtT, HD, HD);
  convT_f32_f16<<<dim3(24, 8), blk, 0, stream>>>(Wo, WoT, 1536, HD);

  gemm_f16<1,0><<<dim3(64, 8), blk, 0, stream>>>(query_h, nullptr, nullptr, WqT, bq, q_h, nullptr, MQ, HD);
  gemm_f16<1,3><<<dim3(32, 8), blk, 0, stream>>>(src_h, nullptr, nullptr, WsT, bs, skey, skeyT, 2048, HD);
  gemm_f16<1,3><<<dim3(32, 8), blk, 0, stream>>>(trg_h, nullptr, nullptr, WtT, bt, tkey, tkeyT, 2048, HD);
  write_pad_f16<<<dim3(32), blk, 0, stream>>>(skey, bs, tkey, bt, skeyT, tkeyT);

  border_kernel<<<dim3(128), blk, 0, stream>>>(q_h, skey, tkey, Sb);
  attn_core<<<dim3(MQ), blk, 0, stream>>>(q_h, skey, tkey, Sb, wsn, wtn);
  ctx_gemm<<<dim3(32, 4, 8), blk, 0, stream>>>(wsn, wtn, skeyT, tkeyT, sctx, tctx);

  gemm_f16<3,2><<<dim3(64, 8), blk, 0, stream>>>(query_h, sctx, tctx, WoT, bo, out, nullptr, MQ, HD);
}

// Round 7
// 192.880 us; speedup vs baseline: 1.9442x; 1.0355x over previous
//
#include <hip/hip_runtime.h>
#include <math.h>

// Problem constants (fixed by the reference)
#define HD 512          // Q_DIM = F_DIM = H_DIM = OUT_DIM = 512
#define SP 129          // S+1 = T+1
#define RPAD 144        // padded key rows per batch (129 used, rest zero; 9x16)
#define WPAD 160        // padded weight-vector length (129 used, rest zero)
#define NBATCH 16
#define MQ 4096         // 16*256 query rows
#define SCALE 0.04419417382415922f        // 1/sqrt(512)
#define SCLG2E 0.06375871645788f          // SCALE * log2(e)
#define TANH2E 2.8853900817779268f        // 2 * log2(e)

typedef _Float16 f16;
typedef _Float16 f16x8 __attribute__((ext_vector_type(8)));
typedef _Float16 f16x4 __attribute__((ext_vector_type(4)));
typedef float f32x4  __attribute__((ext_vector_type(4)));

__device__ __forceinline__ void gload_lds16(const f16* g, f16* l) {
  __builtin_amdgcn_global_load_lds(
      (const __attribute__((address_space(1))) void*)g,
      (__attribute__((address_space(3))) void*)l, 16, 0, 0);
}

// ---------------------------------------------------------------------------
// prep: 4 weight transposes (f32 [K][512] -> f16 [512|...][K]) + key pad fill.
// blocks 0..63 Wq, 64..127 Ws, 128..191 Wt, 192..383 Wo, 384..415 pads.
// ---------------------------------------------------------------------------
__global__ __launch_bounds__(256) void prep_kernel(
    const float* __restrict__ Wq, const float* __restrict__ Ws,
    const float* __restrict__ Wt, const float* __restrict__ Wo,
    const float* __restrict__ bs, const float* __restrict__ bt,
    f16* __restrict__ WqT, f16* __restrict__ WsT,
    f16* __restrict__ WtT, f16* __restrict__ WoT,
    f16* __restrict__ skey, f16* __restrict__ tkey,
    f16* __restrict__ skeyT, f16* __restrict__ tkeyT)
{
  const int id = blockIdx.x;
  const int tid = threadIdx.x;
  if (id >= 384) {   // pad fill: key rows 128..143 (row128=bias), keyT cols
    int i = (id - 384) * 256 + tid;    // 16*512
    int b = i >> 9, n = i & 511;
    for (int r = 128; r < RPAD; ++r) {
      skey[((size_t)b*RPAD + r)*HD + n] = (r == 128) ? (f16)bs[n] : (f16)0.f;
      tkey[((size_t)b*RPAD + r)*HD + n] = (r == 128) ? (f16)bt[n] : (f16)0.f;
    }
    size_t o = ((size_t)b*512 + n)*WPAD;
    for (int c = 128; c < WPAD; ++c) {
      skeyT[o + c] = (c == 128) ? (f16)bs[n] : (f16)0.f;
      tkeyT[o + c] = (c == 128) ? (f16)bt[n] : (f16)0.f;
    }
    return;
  }
  const float* W; f16* WT; int K; int rest;
  if (id < 64)       { W = Wq; WT = WqT; K = 512;  rest = id; }
  else if (id < 128) { W = Ws; WT = WsT; K = 512;  rest = id - 64; }
  else if (id < 192) { W = Wt; WT = WtT; K = 512;  rest = id - 128; }
  else               { W = Wo; WT = WoT; K = 1536; rest = id - 192; }
  const int k0 = (rest >> 3) * 64, n0 = (rest & 7) * 64;

  __shared__ float t[64][65];
  const int r = tid >> 4, c4 = (tid & 15) * 4;
  #pragma unroll
  for (int i = 0; i < 4; ++i) {
    int k = r + 16*i;
    float4 v = *(const float4*)(W + (size_t)(k0 + k)*512 + n0 + c4);
    t[k][c4] = v.x; t[k][c4+1] = v.y; t[k][c4+2] = v.z; t[k][c4+3] = v.w;
  }
  __syncthreads();
  #pragma unroll
  for (int i = 0; i < 4; ++i) {
    int n = r + 16*i;
    f16x4 v = { (f16)t[c4][n], (f16)t[c4+1][n], (f16)t[c4+2][n], (f16)t[c4+3][n] };
    *(f16x4*)(WT + (size_t)(n0 + n)*K + k0 + c4) = v;
  }
}

// ---------------------------------------------------------------------------
// Merged input GEMMs (f32 A converted in staging):
// x<64: q_h = query@WqT^T+bq ; 64..95: skey(+skeyT) ; 96..127: tkey(+tkeyT)
// ---------------------------------------------------------------------------
__global__ __launch_bounds__(256) void gemm_in(
    const float* __restrict__ query, const float* __restrict__ src,
    const float* __restrict__ trg,
    const f16* __restrict__ WqT, const f16* __restrict__ WsT,
    const f16* __restrict__ WtT,
    const float* __restrict__ bq, const float* __restrict__ bsv,
    const float* __restrict__ btv,
    f16* __restrict__ q_h, f16* __restrict__ skey, f16* __restrict__ tkey,
    f16* __restrict__ skeyT, f16* __restrict__ tkeyT)
{
  __shared__ __align__(16) f16 As[64*64];
  __shared__ __align__(16) f16 Bs[64*64];
  const int x = blockIdx.x;
  const float* A; const f16* WT; const float* bias; int bm; int iskey;
  f16 *Ch, *CT;
  if (x < 64)      { A = query; WT = WqT; bias = bq;  bm = x*64;      iskey = 0; Ch = q_h;  CT = nullptr; }
  else if (x < 96) { A = src;   WT = WsT; bias = bsv; bm = (x-64)*64; iskey = 1; Ch = skey; CT = skeyT; }
  else             { A = trg;   WT = WtT; bias = btv; bm = (x-96)*64; iskey = 1; Ch = tkey; CT = tkeyT; }
  const int bn = blockIdx.y * 64;
  const int tid  = threadIdx.x;
  const int lane = tid & 63;
  const int w    = tid >> 6;
  const int wr   = w & 1, wc = w >> 1;
  const int fq   = lane >> 4, fr = lane & 15;

  f32x4 acc[2][2] = {};

  for (int k0 = 0; k0 < 512; k0 += 64) {
    #pragma unroll
    for (int i = 0; i < 2; ++i) {
      int idx = tid + 256*i;
      int r = idx >> 3, c = idx & 7;
      const float* ap = A + (size_t)(bm + r)*512 + k0 + c*8;
      float4 x0 = *(const float4*)ap;
      float4 x1 = *(const float4*)(ap + 4);
      f16x8 va = { (f16)x0.x, (f16)x0.y, (f16)x0.z, (f16)x0.w,
                   (f16)x1.x, (f16)x1.y, (f16)x1.z, (f16)x1.w };
      const uint4 vb = *(const uint4*)(WT + (size_t)(bn + r)*512 + k0 + c*8);
      int o = ((r << 7) + (c << 4)) ^ ((r & 7) << 4);
      *(f16x8*)((char*)As + o) = va;
      *(uint4*)((char*)Bs + o) = vb;
    }
    __syncthreads();
    #pragma unroll
    for (int ks = 0; ks < 2; ++ks) {
      f16x8 af[2], bf_[2];
      #pragma unroll
      for (int i = 0; i < 2; ++i) {
        int ra = wr*32 + i*16 + fr;
        int oa = ((ra << 7) + (ks << 6) + (fq << 4)) ^ ((ra & 7) << 4);
        af[i] = *(const f16x8*)((const char*)As + oa);
        int rb = wc*32 + i*16 + fr;
        int ob = ((rb << 7) + (ks << 6) + (fq << 4)) ^ ((rb & 7) << 4);
        bf_[i] = *(const f16x8*)((const char*)Bs + ob);
      }
      #pragma unroll
      for (int i = 0; i < 2; ++i)
        #pragma unroll
        for (int j = 0; j < 2; ++j)
          acc[i][j] = __builtin_amdgcn_mfma_f32_16x16x32_f16(af[i], bf_[j], acc[i][j], 0, 0, 0);
    }
    __syncthreads();
  }

  #pragma unroll
  for (int i = 0; i < 2; ++i) {
    #pragma unroll
    for (int j = 0; j < 2; ++j) {
      int n = bn + wc*32 + j*16 + fr;
      float bv = bias[n];
      if (iskey) {
        const int m0 = bm + wr*32 + i*16 + fq*4;
        f16 vals[4];
        #pragma unroll
        for (int r = 0; r < 4; ++r) {
          int m = m0 + r;
          f16 xx = (f16)(acc[i][j][r] + bv);
          vals[r] = xx;
          int mo = (m >> 7) * RPAD + (m & 127);
          Ch[(size_t)mo*512 + n] = xx;
        }
        f16x4 v4 = { vals[0], vals[1], vals[2], vals[3] };
        *(f16x4*)(CT + ((size_t)(m0 >> 7)*512 + n)*WPAD + (m0 & 127)) = v4;
      } else {
        #pragma unroll
        for (int r = 0; r < 4; ++r) {
          int m = bm + wr*32 + i*16 + fq*4 + r;
          Ch[(size_t)m*512 + n] = (f16)(acc[i][j][r] + bv);
        }
      }
    }
  }
}

// ---------------------------------------------------------------------------
// Border scores (raw, f32): Sb[0][l][t] = sum_k q[l,k]*sk128[k]*tk[t,k]
//                           Sb[1][l][s] = sum_k q[l,k]*tk128[k]*sk[s,k]
// grid 128 blocks: b(16) x z(2) x mt(4); block = 64 l-rows x 144 cols.
// LDS reads/writes slot-swizzled (c ^ ((row>>1)&3)) -> conflict-free.
// ---------------------------------------------------------------------------
__global__ __launch_bounds__(256) void border_kernel(
    const f16* __restrict__ q_h, const f16* __restrict__ skey,
    const f16* __restrict__ tkey, float* __restrict__ Sb)
{
  const int blk = blockIdx.x;
  const int b = blk >> 3, z = (blk >> 2) & 1, mt = blk & 3;
  const f16* keys = (z ? skey : tkey) + (size_t)b*RPAD*HD;
  const f16* u    = (z ? tkey : skey) + ((size_t)b*RPAD + 128)*HD;
  const int gid0 = b*256 + mt*64;

  __shared__ __align__(16) f16 Ks[RPAD*32];
  const int tid = threadIdx.x, lane = tid & 63, w = tid >> 6;
  const int fq = lane >> 4, fr = lane & 15;
  const int wslot = ((tid & 3) ^ ((tid >> 3) & 3)) * 8;   // write slot
  const int rslot = ((fq ^ ((fr >> 1) & 3))) * 8;         // read slot

  f32x4 acc[9] = {};

  for (int kt = 0; kt < 16; ++kt) {
    uint4 t0, t1, t2;
    {
      int r0 = tid >> 2, c0 = tid & 3;
      t0 = *(const uint4*)(keys + (size_t)r0*HD + kt*32 + c0*8);
      int r1 = (tid + 256) >> 2;
      t1 = *(const uint4*)(keys + (size_t)r1*HD + kt*32 + c0*8);
      if (tid < 64) {
        int r2 = (tid + 512) >> 2;
        t2 = *(const uint4*)(keys + (size_t)r2*HD + kt*32 + c0*8);
      }
    }
    __syncthreads();
    {
      int r0 = tid >> 2;
      *(uint4*)(&Ks[r0*32 + wslot]) = t0;
      int r1 = (tid + 256) >> 2;
      *(uint4*)(&Ks[r1*32 + wslot]) = t1;
      if (tid < 64) {
        int r2 = (tid + 512) >> 2;
        *(uint4*)(&Ks[r2*32 + wslot]) = t2;
      }
    }
    __syncthreads();
    const f16x8 qf = *(const f16x8*)(q_h + (size_t)(gid0 + w*16 + fr)*HD + kt*32 + fq*8);
    const f16x8 uv = *(const f16x8*)(u + kt*32 + fq*8);
    const f16x8 a = qf * uv;
    #pragma unroll
    for (int j = 0; j < 9; ++j) {
      const f16x8 bfr = *(const f16x8*)(&Ks[(j*16 + fr)*32 + rslot]);
      acc[j] = __builtin_amdgcn_mfma_f32_16x16x32_f16(a, bfr, acc[j], 0, 0, 0);
    }
  }

  float* dst = Sb + (size_t)z*MQ*RPAD;
  #pragma unroll
  for (int j = 0; j < 9; ++j)
    #pragma unroll
    for (int r = 0; r < 4; ++r)
      dst[(size_t)(gid0 + w*16 + fq*4 + r)*RPAD + j*16 + fr] = acc[j][r];
}

// ---------------------------------------------------------------------------
// Core trilinear attention: 1 query row / block, 4 waves, 128x128 core only.
// KB layout: [buf][key][row(128)][4 slots x 8 f16], slot = chunk ^ ((row>>1)&3)
// (both-sides swizzle: gload_lds linear dest + permuted global source).
// Outputs normalized weights wsn/wtn [4096][160] f16.
// ---------------------------------------------------------------------------
__global__ __launch_bounds__(256, 4) void attn_core(
    const f16* __restrict__ qg,      // (4096, 512)
    const f16* __restrict__ skey,    // (16, 144, 512)
    const f16* __restrict__ tkey,    // (16, 144, 512)
    const float* __restrict__ Sb,    // (2, 4096, 144) raw border scores
    f16* __restrict__ wsn,           // (4096, 160) normalized row weights
    f16* __restrict__ wtn)           // (4096, 160) normalized col weights
{
  __shared__ __align__(16) f16 KB[2*2*128*32];   // 32 KB
  __shared__ __align__(16) f16 qs[HD];
  __shared__ float wsA[2][128];
  __shared__ float wtA[2][128];
  __shared__ float redA[4], redB[4], redC[4], redD[4], redE[4];
  __shared__ float cornerP;

  const int tid  = threadIdx.x;
  const int lane = tid & 63;
  const int w    = tid >> 6;
  const int rb   = w & 1;    // row half (s tiles 0..3 / 4..7)
  const int cb   = w >> 1;   // col half
  const int fq   = lane >> 4;
  const int fr   = lane & 15;
  const int so   = (fq ^ ((fr >> 1) & 3)) << 3;   // read slot byte/2 offset
  const int gc   = ((lane & 3) ^ ((lane >> 3) & 3)) * 8;  // staged global chunk

  // XCD-chunked swizzle: 4096 blocks -> 512 consecutive rows per XCD
  const int gid = ((int)blockIdx.x & 7) * 512 + ((int)blockIdx.x >> 3);
  const int b   = gid >> 8;
  const f16* skg = skey + (size_t)b * RPAD * HD;
  const f16* tkg = tkey + (size_t)b * RPAD * HD;

  if (tid < 64) *(uint4*)(qs + tid*8) = *(const uint4*)(qg + (size_t)gid*HD + tid*8);

  // stage one K=32 tile of both keys (16 wave-insts; 4 per wave)
  auto stage = [&](int kt, int buf) {
    #pragma unroll
    for (int n = 0; n < 4; ++n) {
      int idx = w*4 + n;             // 0..15
      int key = idx >> 3;
      int rg  = idx & 7;             // 16-row group
      const f16* g = (key ? tkg : skg)
                   + (size_t)(rg*16 + (lane >> 2))*HD + kt*32 + gc;
      f16* l = &KB[((buf*2 + key)*128 + rg*16)*32];
      gload_lds16(g, l);
    }
  };

  f32x4 acc[4][4] = {};

  auto mfma_kt = [&](int kt, int cur) {
    const f16x8 qv = *(const f16x8*)(&qs[kt*32 + fq*8]);
    const int abase = (cur*2 + 0)*128*32;
    const int bbase = (cur*2 + 1)*128*32;
    f16x8 B[4];
    #pragma unroll
    for (int j = 0; j < 4; ++j) {
      int rt = cb*64 + j*16 + fr;
      B[j] = *(const f16x8*)(&KB[bbase + rt*32 + so]);
    }
    __builtin_amdgcn_s_setprio(1);
    #pragma unroll
    for (int i = 0; i < 4; ++i) {
      int rs = rb*64 + i*16 + fr;
      const f16x8 raw = *(const f16x8*)(&KB[abase + rs*32 + so]);
      const f16x8 a = raw * qv;      // v_pk_mul_f16
      #pragma unroll
      for (int j = 0; j < 4; ++j)
        acc[i][j] = __builtin_amdgcn_mfma_f32_16x16x32_f16(a, B[j], acc[i][j], 0, 0, 0);
    }
    __builtin_amdgcn_s_setprio(0);
  };

  stage(0, 0);
  __syncthreads();                    // drains vmcnt(0); qs visible

  for (int kt = 0; kt < 16; ++kt) {
    const int cur = kt & 1;
    if (kt < 15) {
      stage(kt + 1, cur ^ 1);
      asm volatile("s_waitcnt vmcnt(4)" ::: "memory");   // prev tile landed
    } else {
      asm volatile("s_waitcnt vmcnt(0)" ::: "memory");
    }
    __builtin_amdgcn_s_barrier();
    mfma_kt(kt, cur);
    __builtin_amdgcn_s_barrier();
  }

  // ---- max: core (regs) + border (global) ----
  float m = -3e38f;
  #pragma unroll
  for (int i = 0; i < 4; ++i)
    #pragma unroll
    for (int j = 0; j < 4; ++j)
      #pragma unroll
      for (int r = 0; r < 4; ++r) m = fmaxf(m, acc[i][j][r]);
  #pragma unroll
  for (int off = 32; off > 0; off >>= 1) m = fmaxf(m, __shfl_xor(m, off));
  if (lane == 0) redA[w] = m;

  const float* SbT = Sb + (size_t)gid*RPAD;
  const float* SbS = Sb + (size_t)MQ*RPAD + (size_t)gid*RPAD;
  const float btv = (tid < 129) ? SbT[tid] : -3e38f;
  const float bsv = (tid < 128) ? SbS[tid] : -3e38f;
  float bm = fmaxf(btv, bsv);
  #pragma unroll
  for (int off = 32; off > 0; off >>= 1) bm = fmaxf(bm, __shfl_xor(bm, off));
  if (lane == 0) redB[w] = bm;
  __syncthreads();
  const float mraw = fmaxf(
      fmaxf(fmaxf(redA[0], redA[1]), fmaxf(redA[2], redA[3])),
      fmaxf(fmaxf(redB[0], redB[1]), fmaxf(redB[2], redB[3])));

  // ---- exp core + core sum (exp2 with folded constant) ----
  float csum = 0.f;
  #pragma unroll
  for (int i = 0; i < 4; ++i)
    #pragma unroll
    for (int j = 0; j < 4; ++j)
      #pragma unroll
      for (int r = 0; r < 4; ++r) {
        float p = exp2f((acc[i][j][r] - mraw) * SCLG2E);
        acc[i][j][r] = p;
        csum += p;
      }
  #pragma unroll
  for (int off = 32; off > 0; off >>= 1) csum += __shfl_xor(csum, off);
  if (lane == 0) redC[w] = csum;

  // ---- row sums (over this wave's 4 col-tiles) ----
  #pragma unroll
  for (int i = 0; i < 4; ++i) {
    #pragma unroll
    for (int r = 0; r < 4; ++r) {
      float rs = acc[i][0][r] + acc[i][1][r] + acc[i][2][r] + acc[i][3][r];
      rs += __shfl_xor(rs, 1); rs += __shfl_xor(rs, 2);
      rs += __shfl_xor(rs, 4); rs += __shfl_xor(rs, 8);
      if (fr == 0) wsA[cb][rb*64 + i*16 + fq*4 + r] = rs;
    }
  }
  // ---- col sums (over this wave's 4 row-tiles) ----
  #pragma unroll
  for (int j = 0; j < 4; ++j) {
    float cs = 0.f;
    #pragma unroll
    for (int i = 0; i < 4; ++i)
      #pragma unroll
      for (int r = 0; r < 4; ++r) cs += acc[i][j][r];
    cs += __shfl_xor(cs, 16); cs += __shfl_xor(cs, 32);
    if (fq == 0) wtA[rb][cb*64 + j*16 + fr] = cs;
  }

  // ---- border exps + sums ----
  const float pbt = (tid < 129) ? exp2f((btv - mraw) * SCLG2E) : 0.f;
  const float pbs = (tid < 128) ? exp2f((bsv - mraw) * SCLG2E) : 0.f;
  float sbt = pbt, sbs = pbs;
  #pragma unroll
  for (int off = 32; off > 0; off >>= 1) {
    sbt += __shfl_xor(sbt, off);
    sbs += __shfl_xor(sbs, off);
  }
  if (lane == 0) { redD[w] = sbt; redE[w] = sbs; }
  if (tid == 128) cornerP = pbt;
  __syncthreads();

  const float pbt_sum = redD[0] + redD[1] + redD[2] + redD[3];
  const float pbs_sum = redE[0] + redE[1] + redE[2] + redE[3];
  const float core_sum = redC[0] + redC[1] + redC[2] + redC[3];
  const float invZ = 1.0f / (core_sum + pbt_sum + pbs_sum);

  if (tid < WPAD) {
    float wsv = (tid < 128) ? (wsA[0][tid] + wsA[1][tid] + pbs)
              : (tid == 128) ? pbt_sum : 0.f;
    float wtv = (tid < 128) ? (wtA[0][tid] + wtA[1][tid] + pbt)
              : (tid == 128) ? (pbs_sum + cornerP) : 0.f;
    wsn[(size_t)gid*WPAD + tid] = (f16)(wsv * invZ);
    wtn[(size_t)gid*WPAD + tid] = (f16)(wtv * invZ);
  }
}

// ---------------------------------------------------------------------------
// ctx GEMM: sctx[l][hd] = sum_s wsn[l][s] * skey[s][hd]  (keyT pre-transposed)
// ---------------------------------------------------------------------------
__global__ __launch_bounds__(256) void ctx_gemm(
    const f16* __restrict__ wsn, const f16* __restrict__ wtn,
    const f16* __restrict__ skeyT, const f16* __restrict__ tkeyT,
    f16* __restrict__ sctx, f16* __restrict__ tctx)
{
  __shared__ __align__(16) f16 As[64*168];
  __shared__ __align__(16) f16 Bs[64*168];
  const int z = blockIdx.x & 1, b = blockIdx.x >> 1;
  const int mt = blockIdx.y, nt = blockIdx.z;
  const int tid = threadIdx.x, lane = tid & 63, w = tid >> 6;
  const int wr = w & 1, wc = w >> 1;
  const int fq = lane >> 4, fr = lane & 15;

  const f16* A  = (z ? wtn : wsn) + ((size_t)b*256 + mt*64)*WPAD;
  const f16* Bt = (z ? tkeyT : skeyT) + ((size_t)b*512 + nt*64)*WPAD;

  for (int t = tid; t < 1280; t += 256) {
    int r = t / 20, c = t % 20;
    *(uint4*)(&As[r*168 + c*8]) = *(const uint4*)(A + (size_t)r*WPAD + c*8);
    *(uint4*)(&Bs[r*168 + c*8]) = *(const uint4*)(Bt + (size_t)r*WPAD + c*8);
  }
  __syncthreads();

  f32x4 acc[2][2] = {};
  #pragma unroll
  for (int ks = 0; ks < 5; ++ks) {
    f16x8 af[2], bf_[2];
    #pragma unroll
    for (int i = 0; i < 2; ++i) {
      af[i]  = *(const f16x8*)(&As[(wr*32 + i*16 + fr)*168 + ks*32 + fq*8]);
      bf_[i] = *(const f16x8*)(&Bs[(wc*32 + i*16 + fr)*168 + ks*32 + fq*8]);
    }
    #pragma unroll
    for (int i = 0; i < 2; ++i)
      #pragma unroll
      for (int j = 0; j < 2; ++j)
        acc[i][j] = __builtin_amdgcn_mfma_f32_16x16x32_f16(af[i], bf_[j], acc[i][j], 0, 0, 0);
  }

  f16* out = z ? tctx : sctx;
  #pragma unroll
  for (int i = 0; i < 2; ++i)
    #pragma unroll
    for (int j = 0; j < 2; ++j) {
      int col = nt*64 + wc*32 + j*16 + fr;
      #pragma unroll
      for (int r = 0; r < 4; ++r) {
        int row = b*256 + mt*64 + wr*32 + i*16 + fq*4 + r;
        out[(size_t)row*HD + col] = (f16)acc[i][j][r];
      }
    }
}

// ---------------------------------------------------------------------------
// out = tanh([query(f32) | sctx | tctx] @ WoT^T + bo), K = 1536, f32 out.
// ---------------------------------------------------------------------------
__global__ __launch_bounds__(256) void gemm_out(
    const float* __restrict__ query, const f16* __restrict__ sctx,
    const f16* __restrict__ tctx, const f16* __restrict__ WoT,
    const float* __restrict__ bias, float* __restrict__ C)
{
  __shared__ __align__(16) f16 As[64*64];
  __shared__ __align__(16) f16 Bs[64*64];
  const int tid  = threadIdx.x;
  const int lane = tid & 63;
  const int w    = tid >> 6;
  const int wr   = w & 1, wc = w >> 1;
  const int fq   = lane >> 4, fr = lane & 15;
  const int bm = blockIdx.x * 64, bn = blockIdx.y * 64;

  f32x4 acc[2][2] = {};

  for (int k0 = 0; k0 < 1536; k0 += 64) {
    const int seg  = k0 >> 9;
    const int kloc = k0 & 511;
    #pragma unroll
    for (int i = 0; i < 2; ++i) {
      int idx = tid + 256*i;
      int r = idx >> 3, c = idx & 7;
      int o = ((r << 7) + (c << 4)) ^ ((r & 7) << 4);
      if (seg == 0) {
        const float* ap = query + (size_t)(bm + r)*512 + kloc + c*8;
        float4 x0 = *(const float4*)ap;
        float4 x1 = *(const float4*)(ap + 4);
        f16x8 va = { (f16)x0.x, (f16)x0.y, (f16)x0.z, (f16)x0.w,
                     (f16)x1.x, (f16)x1.y, (f16)x1.z, (f16)x1.w };
        *(f16x8*)((char*)As + o) = va;
      } else {
        const f16* Ap = (seg == 1) ? sctx : tctx;
        *(uint4*)((char*)As + o) = *(const uint4*)(Ap + (size_t)(bm + r)*512 + kloc + c*8);
      }
      *(uint4*)((char*)Bs + o) = *(const uint4*)(WoT + (size_t)(bn + r)*1536 + k0 + c*8);
    }
    __syncthreads();
    #pragma unroll
    for (int ks = 0; ks < 2; ++ks) {
      f16x8 af[2], bf_[2];
      #pragma unroll
      for (int i = 0; i < 2; ++i) {
        int ra = wr*32 + i*16 + fr;
        int oa = ((ra << 7) + (ks << 6) + (fq << 4)) ^ ((ra & 7) << 4);
        af[i] = *(const f16x8*)((const char*)As + oa);
        int rb = wc*32 + i*16 + fr;
        int ob = ((rb << 7) + (ks << 6) + (fq << 4)) ^ ((rb & 7) << 4);
        bf_[i] = *(const f16x8*)((const char*)Bs + ob);
      }
      #pragma unroll
      for (int i = 0; i < 2; ++i)
        #pragma unroll
        for (int j = 0; j < 2; ++j)
          acc[i][j] = __builtin_amdgcn_mfma_f32_16x16x32_f16(af[i], bf_[j], acc[i][j], 0, 0, 0);
    }
    __syncthreads();
  }

  #pragma unroll
  for (int i = 0; i < 2; ++i)
    #pragma unroll
    for (int j = 0; j < 2; ++j) {
      int n = bn + wc*32 + j*16 + fr;
      float bv = bias[n];
      #pragma unroll
      for (int r = 0; r < 4; ++r) {
        int m = bm + wr*32 + i*16 + fq*4 + r;
        float xx = acc[i][j][r] + bv;
        xx = fminf(fmaxf(xx, -20.f), 20.f);
        float e = exp2f(TANH2E * xx);
        C[(size_t)m*HD + n] = (e - 1.0f) / (e + 1.0f);
      }
    }
}

extern "C" void kernel_launch(void* const* d_in, const int* in_sizes, int n_in,
                              void* d_out, int out_size, void* d_ws, size_t ws_size,
                              hipStream_t stream) {
  (void)in_sizes; (void)n_in; (void)out_size; (void)ws_size;
  const float* query = (const float*)d_in[0];
  const float* src   = (const float*)d_in[1];
  const float* trg   = (const float*)d_in[2];
  const float* Wq    = (const float*)d_in[3];
  const float* bq    = (const float*)d_in[4];
  const float* Wsm   = (const float*)d_in[5];
  const float* bs    = (const float*)d_in[6];
  const float* Wtm   = (const float*)d_in[7];
  const float* bt    = (const float*)d_in[8];
  const float* Wo    = (const float*)d_in[9];
  const float* bo    = (const float*)d_in[10];
  float* out = (float*)d_out;

  // workspace layout (~32 MB)
  char* p = (char*)d_ws;
  f16* WqT   = (f16*)p;  p += (size_t)HD*HD*2;
  f16* WsT   = (f16*)p;  p += (size_t)HD*HD*2;
  f16* WtT   = (f16*)p;  p += (size_t)HD*HD*2;
  f16* WoT   = (f16*)p;  p += (size_t)1536*HD*2;
  f16* q_h   = (f16*)p;  p += (size_t)MQ*HD*2;
  f16* skey  = (f16*)p;  p += (size_t)NBATCH*RPAD*HD*2;
  f16* tkey  = (f16*)p;  p += (size_t)NBATCH*RPAD*HD*2;
  f16* skeyT = (f16*)p;  p += (size_t)NBATCH*HD*WPAD*2;
  f16* tkeyT = (f16*)p;  p += (size_t)NBATCH*HD*WPAD*2;
  f16* wsn   = (f16*)p;  p += (size_t)MQ*WPAD*2;
  f16* wtn   = (f16*)p;  p += (size_t)MQ*WPAD*2;
  f16* sctx  = (f16*)p;  p += (size_t)MQ*HD*2;
  f16* tctx  = (f16*)p;  p += (size_t)MQ*HD*2;
  float* Sb  = (float*)p; p += (size_t)2*MQ*RPAD*4;

  dim3 blk(256);
  prep_kernel<<<dim3(416), blk, 0, stream>>>(Wq, Wsm, Wtm, Wo, bs, bt,
                                             WqT, WsT, WtT, WoT,
                                             skey, tkey, skeyT, tkeyT);
  gemm_in<<<dim3(128, 8), blk, 0, stream>>>(query, src, trg, WqT, WsT, WtT,
                                            bq, bs, bt, q_h, skey, tkey,
                                            skeyT, tkeyT);
  border_kernel<<<dim3(128), blk, 0, stream>>>(q_h, skey, tkey, Sb);
  attn_core<<<dim3(MQ), blk, 0, stream>>>(q_h, skey, tkey, Sb, wsn, wtn);
  ctx_gemm<<<dim3(32, 4, 8), blk, 0, stream>>>(wsn, wtn, skeyT, tkeyT, sctx, tctx);
  gemm_out<<<dim3(64, 8), blk, 0, stream>>>(query, sctx, tctx, WoT, bo, out);
}

// Round 8
// 191.788 us; speedup vs baseline: 1.9553x; 1.0057x over previous
//
#include <hip/hip_runtime.h>
#include <math.h>

// Problem constants (fixed by the reference)
#define HD 512          // Q_DIM = F_DIM = H_DIM = OUT_DIM = 512
#define SP 129          // S+1 = T+1
#define RPAD 144        // padded key rows per batch (129 used, rest zero; 9x16)
#define WPAD 160        // padded weight-vector length (129 used, rest zero)
#define NBATCH 16
#define MQ 4096         // 16*256 query rows
#define SCALE 0.04419417382415922f        // 1/sqrt(512)
#define SCLG2E 0.06375871645788f          // SCALE * log2(e)
#define TANH2E 2.8853900817779268f        // 2 * log2(e)

typedef _Float16 f16;
typedef _Float16 f16x8 __attribute__((ext_vector_type(8)));
typedef _Float16 f16x4 __attribute__((ext_vector_type(4)));
typedef float f32x4  __attribute__((ext_vector_type(4)));

__device__ __forceinline__ void gload_lds16(const f16* g, f16* l) {
  __builtin_amdgcn_global_load_lds(
      (const __attribute__((address_space(1))) void*)g,
      (__attribute__((address_space(3))) void*)l, 16, 0, 0);
}

// ---------------------------------------------------------------------------
// prep: 4 weight transposes (f32 [K][512] -> f16 [512|...][K]) + key pad fill.
// blocks 0..63 Wq, 64..127 Ws, 128..191 Wt, 192..383 Wo, 384..415 pads.
// ---------------------------------------------------------------------------
__global__ __launch_bounds__(256) void prep_kernel(
    const float* __restrict__ Wq, const float* __restrict__ Ws,
    const float* __restrict__ Wt, const float* __restrict__ Wo,
    const float* __restrict__ bs, const float* __restrict__ bt,
    f16* __restrict__ WqT, f16* __restrict__ WsT,
    f16* __restrict__ WtT, f16* __restrict__ WoT,
    f16* __restrict__ skey, f16* __restrict__ tkey,
    f16* __restrict__ skeyT, f16* __restrict__ tkeyT)
{
  const int id = blockIdx.x;
  const int tid = threadIdx.x;
  if (id >= 384) {   // pad fill: key rows 128..143 (row128=bias), keyT cols
    int i = (id - 384) * 256 + tid;    // 16*512
    int b = i >> 9, n = i & 511;
    for (int r = 128; r < RPAD; ++r) {
      skey[((size_t)b*RPAD + r)*HD + n] = (r == 128) ? (f16)bs[n] : (f16)0.f;
      tkey[((size_t)b*RPAD + r)*HD + n] = (r == 128) ? (f16)bt[n] : (f16)0.f;
    }
    size_t o = ((size_t)b*512 + n)*WPAD;
    for (int c = 128; c < WPAD; ++c) {
      skeyT[o + c] = (c == 128) ? (f16)bs[n] : (f16)0.f;
      tkeyT[o + c] = (c == 128) ? (f16)bt[n] : (f16)0.f;
    }
    return;
  }
  const float* W; f16* WT; int K; int rest;
  if (id < 64)       { W = Wq; WT = WqT; K = 512;  rest = id; }
  else if (id < 128) { W = Ws; WT = WsT; K = 512;  rest = id - 64; }
  else if (id < 192) { W = Wt; WT = WtT; K = 512;  rest = id - 128; }
  else               { W = Wo; WT = WoT; K = 1536; rest = id - 192; }
  const int k0 = (rest >> 3) * 64, n0 = (rest & 7) * 64;

  __shared__ float t[64][65];
  const int r = tid >> 4, c4 = (tid & 15) * 4;
  #pragma unroll
  for (int i = 0; i < 4; ++i) {
    int k = r + 16*i;
    float4 v = *(const float4*)(W + (size_t)(k0 + k)*512 + n0 + c4);
    t[k][c4] = v.x; t[k][c4+1] = v.y; t[k][c4+2] = v.z; t[k][c4+3] = v.w;
  }
  __syncthreads();
  #pragma unroll
  for (int i = 0; i < 4; ++i) {
    int n = r + 16*i;
    f16x4 v = { (f16)t[c4][n], (f16)t[c4+1][n], (f16)t[c4+2][n], (f16)t[c4+3][n] };
    *(f16x4*)(WT + (size_t)(n0 + n)*K + k0 + c4) = v;
  }
}

// ---------------------------------------------------------------------------
// Merged input GEMMs (f32 A converted in staging):
// x<64: q_h = query@WqT^T+bq ; 64..95: skey(+skeyT) ; 96..127: tkey(+tkeyT)
// ---------------------------------------------------------------------------
__global__ __launch_bounds__(256) void gemm_in(
    const float* __restrict__ query, const float* __restrict__ src,
    const float* __restrict__ trg,
    const f16* __restrict__ WqT, const f16* __restrict__ WsT,
    const f16* __restrict__ WtT,
    const float* __restrict__ bq, const float* __restrict__ bsv,
    const float* __restrict__ btv,
    f16* __restrict__ q_h, f16* __restrict__ skey, f16* __restrict__ tkey,
    f16* __restrict__ skeyT, f16* __restrict__ tkeyT)
{
  __shared__ __align__(16) f16 As[64*64];
  __shared__ __align__(16) f16 Bs[64*64];
  const int x = blockIdx.x;
  const float* A; const f16* WT; const float* bias; int bm; int iskey;
  f16 *Ch, *CT;
  if (x < 64)      { A = query; WT = WqT; bias = bq;  bm = x*64;      iskey = 0; Ch = q_h;  CT = nullptr; }
  else if (x < 96) { A = src;   WT = WsT; bias = bsv; bm = (x-64)*64; iskey = 1; Ch = skey; CT = skeyT; }
  else             { A = trg;   WT = WtT; bias = btv; bm = (x-96)*64; iskey = 1; Ch = tkey; CT = tkeyT; }
  const int bn = blockIdx.y * 64;
  const int tid  = threadIdx.x;
  const int lane = tid & 63;
  const int w    = tid >> 6;
  const int wr   = w & 1, wc = w >> 1;
  const int fq   = lane >> 4, fr = lane & 15;

  f32x4 acc[2][2] = {};

  for (int k0 = 0; k0 < 512; k0 += 64) {
    #pragma unroll
    for (int i = 0; i < 2; ++i) {
      int idx = tid + 256*i;
      int r = idx >> 3, c = idx & 7;
      const float* ap = A + (size_t)(bm + r)*512 + k0 + c*8;
      float4 x0 = *(const float4*)ap;
      float4 x1 = *(const float4*)(ap + 4);
      f16x8 va = { (f16)x0.x, (f16)x0.y, (f16)x0.z, (f16)x0.w,
                   (f16)x1.x, (f16)x1.y, (f16)x1.z, (f16)x1.w };
      const uint4 vb = *(const uint4*)(WT + (size_t)(bn + r)*512 + k0 + c*8);
      int o = ((r << 7) + (c << 4)) ^ ((r & 7) << 4);
      *(f16x8*)((char*)As + o) = va;
      *(uint4*)((char*)Bs + o) = vb;
    }
    __syncthreads();
    #pragma unroll
    for (int ks = 0; ks < 2; ++ks) {
      f16x8 af[2], bf_[2];
      #pragma unroll
      for (int i = 0; i < 2; ++i) {
        int ra = wr*32 + i*16 + fr;
        int oa = ((ra << 7) + (ks << 6) + (fq << 4)) ^ ((ra & 7) << 4);
        af[i] = *(const f16x8*)((const char*)As + oa);
        int rb = wc*32 + i*16 + fr;
        int ob = ((rb << 7) + (ks << 6) + (fq << 4)) ^ ((rb & 7) << 4);
        bf_[i] = *(const f16x8*)((const char*)Bs + ob);
      }
      #pragma unroll
      for (int i = 0; i < 2; ++i)
        #pragma unroll
        for (int j = 0; j < 2; ++j)
          acc[i][j] = __builtin_amdgcn_mfma_f32_16x16x32_f16(af[i], bf_[j], acc[i][j], 0, 0, 0);
    }
    __syncthreads();
  }

  #pragma unroll
  for (int i = 0; i < 2; ++i) {
    #pragma unroll
    for (int j = 0; j < 2; ++j) {
      int n = bn + wc*32 + j*16 + fr;
      float bv = bias[n];
      if (iskey) {
        const int m0 = bm + wr*32 + i*16 + fq*4;
        f16 vals[4];
        #pragma unroll
        for (int r = 0; r < 4; ++r) {
          int m = m0 + r;
          f16 xx = (f16)(acc[i][j][r] + bv);
          vals[r] = xx;
          int mo = (m >> 7) * RPAD + (m & 127);
          Ch[(size_t)mo*512 + n] = xx;
        }
        f16x4 v4 = { vals[0], vals[1], vals[2], vals[3] };
        *(f16x4*)(CT + ((size_t)(m0 >> 7)*512 + n)*WPAD + (m0 & 127)) = v4;
      } else {
        #pragma unroll
        for (int r = 0; r < 4; ++r) {
          int m = bm + wr*32 + i*16 + fq*4 + r;
          Ch[(size_t)m*512 + n] = (f16)(acc[i][j][r] + bv);
        }
      }
    }
  }
}

// ---------------------------------------------------------------------------
// Border scores (raw, f32): Sb[0][l][t] = sum_k q[l,k]*sk128[k]*tk[t,k]
//                           Sb[1][l][s] = sum_k q[l,k]*tk128[k]*sk[s,k]
// ---------------------------------------------------------------------------
__global__ __launch_bounds__(256) void border_kernel(
    const f16* __restrict__ q_h, const f16* __restrict__ skey,
    const f16* __restrict__ tkey, float* __restrict__ Sb)
{
  const int blk = blockIdx.x;
  const int b = blk >> 3, z = (blk >> 2) & 1, mt = blk & 3;
  const f16* keys = (z ? skey : tkey) + (size_t)b*RPAD*HD;
  const f16* u    = (z ? tkey : skey) + ((size_t)b*RPAD + 128)*HD;
  const int gid0 = b*256 + mt*64;

  __shared__ __align__(16) f16 Ks[RPAD*32];
  const int tid = threadIdx.x, lane = tid & 63, w = tid >> 6;
  const int fq = lane >> 4, fr = lane & 15;
  const int wslot = ((tid & 3) ^ ((tid >> 3) & 3)) * 8;   // write slot
  const int rslot = ((fq ^ ((fr >> 1) & 3))) * 8;         // read slot

  f32x4 acc[9] = {};

  for (int kt = 0; kt < 16; ++kt) {
    uint4 t0, t1, t2;
    {
      int r0 = tid >> 2, c0 = tid & 3;
      t0 = *(const uint4*)(keys + (size_t)r0*HD + kt*32 + c0*8);
      int r1 = (tid + 256) >> 2;
      t1 = *(const uint4*)(keys + (size_t)r1*HD + kt*32 + c0*8);
      if (tid < 64) {
        int r2 = (tid + 512) >> 2;
        t2 = *(const uint4*)(keys + (size_t)r2*HD + kt*32 + c0*8);
      }
    }
    __syncthreads();
    {
      int r0 = tid >> 2;
      *(uint4*)(&Ks[r0*32 + wslot]) = t0;
      int r1 = (tid + 256) >> 2;
      *(uint4*)(&Ks[r1*32 + wslot]) = t1;
      if (tid < 64) {
        int r2 = (tid + 512) >> 2;
        *(uint4*)(&Ks[r2*32 + wslot]) = t2;
      }
    }
    __syncthreads();
    const f16x8 qf = *(const f16x8*)(q_h + (size_t)(gid0 + w*16 + fr)*HD + kt*32 + fq*8);
    const f16x8 uv = *(const f16x8*)(u + kt*32 + fq*8);
    const f16x8 a = qf * uv;
    #pragma unroll
    for (int j = 0; j < 9; ++j) {
      const f16x8 bfr = *(const f16x8*)(&Ks[(j*16 + fr)*32 + rslot]);
      acc[j] = __builtin_amdgcn_mfma_f32_16x16x32_f16(a, bfr, acc[j], 0, 0, 0);
    }
  }

  float* dst = Sb + (size_t)z*MQ*RPAD;
  #pragma unroll
  for (int j = 0; j < 9; ++j)
    #pragma unroll
    for (int r = 0; r < 4; ++r)
      dst[(size_t)(gid0 + w*16 + fq*4 + r)*RPAD + j*16 + fr] = acc[j][r];
}

// ---------------------------------------------------------------------------
// Core trilinear attention: 2 query rows / block, 4 waves, 128x128 core.
// Shared fragment reads: each A frag scaled by q0 and q1 -> 32 MFMA / 10 reads.
// Quad-buffered K=32 staging (2 tiles ahead), ONE barrier per kt, vmcnt(8).
// KB layout slot-swizzled as r7 (both-sides swizzle, conflict-free).
// ---------------------------------------------------------------------------
__global__ __launch_bounds__(256, 2) void attn_core(
    const f16* __restrict__ qg,      // (4096, 512)
    const f16* __restrict__ skey,    // (16, 144, 512)
    const f16* __restrict__ tkey,    // (16, 144, 512)
    const float* __restrict__ Sb,    // (2, 4096, 144) raw border scores
    f16* __restrict__ wsn,           // (4096, 160) normalized row weights
    f16* __restrict__ wtn)           // (4096, 160) normalized col weights
{
  __shared__ __align__(16) f16 KB[4*2*128*32];   // 64 KB, quad-buffered
  __shared__ __align__(16) f16 qs[2][HD];
  __shared__ float wsA[2][128];
  __shared__ float wtA[2][128];
  __shared__ float redA[4], redB[4], redC[4], redD[4], redE[4];
  __shared__ float cornerP;

  const int tid  = threadIdx.x;
  const int lane = tid & 63;
  const int w    = tid >> 6;
  const int rb   = w & 1;    // row half (s tiles 0..3 / 4..7)
  const int cb   = w >> 1;   // col half
  const int fq   = lane >> 4;
  const int fr   = lane & 15;
  const int so   = (fq ^ ((fr >> 1) & 3)) << 3;            // read slot
  const int gc   = ((lane & 3) ^ ((lane >> 3) & 3)) * 8;   // staged global chunk

  // XCD-chunked swizzle: 2048 blocks -> 256 consecutive pairs per XCD
  const int pair = ((int)blockIdx.x & 7) * 256 + ((int)blockIdx.x >> 3);
  const int gid0 = pair * 2;
  const int b    = gid0 >> 8;
  const f16* skg = skey + (size_t)b * RPAD * HD;
  const f16* tkg = tkey + (size_t)b * RPAD * HD;

  if (tid < 128) {
    int row = tid >> 6, n = tid & 63;
    *(uint4*)(&qs[row][n*8]) = *(const uint4*)(qg + (size_t)(gid0 + row)*HD + n*8);
  }

  // stage one K=32 tile of both keys (16 wave-insts; 4 per wave)
  auto stage = [&](int kt, int buf) {
    #pragma unroll
    for (int n = 0; n < 4; ++n) {
      int idx = w*4 + n;             // 0..15
      int key = idx >> 3;
      int rg  = idx & 7;             // 16-row group
      const f16* g = (key ? tkg : skg)
                   + (size_t)(rg*16 + (lane >> 2))*HD + kt*32 + gc;
      f16* l = &KB[((buf*2 + key)*128 + rg*16)*32];
      gload_lds16(g, l);
    }
  };

  f32x4 acc0[4][4] = {};
  f32x4 acc1[4][4] = {};

  auto mfma_kt = [&](int kt, int buf) {
    const f16x8 qv0 = *(const f16x8*)(&qs[0][kt*32 + fq*8]);
    const f16x8 qv1 = *(const f16x8*)(&qs[1][kt*32 + fq*8]);
    const int abase = (buf*2 + 0)*128*32;
    const int bbase = (buf*2 + 1)*128*32;
    f16x8 B[4];
    #pragma unroll
    for (int j = 0; j < 4; ++j) {
      int rt = cb*64 + j*16 + fr;
      B[j] = *(const f16x8*)(&KB[bbase + rt*32 + so]);
    }
    __builtin_amdgcn_s_setprio(1);
    #pragma unroll
    for (int i = 0; i < 4; ++i) {
      int rs = rb*64 + i*16 + fr;
      const f16x8 raw = *(const f16x8*)(&KB[abase + rs*32 + so]);
      const f16x8 a0 = raw * qv0;    // v_pk_mul_f16
      #pragma unroll
      for (int j = 0; j < 4; ++j)
        acc0[i][j] = __builtin_amdgcn_mfma_f32_16x16x32_f16(a0, B[j], acc0[i][j], 0, 0, 0);
      const f16x8 a1 = raw * qv1;
      #pragma unroll
      for (int j = 0; j < 4; ++j)
        acc1[i][j] = __builtin_amdgcn_mfma_f32_16x16x32_f16(a1, B[j], acc1[i][j], 0, 0, 0);
    }
    __builtin_amdgcn_s_setprio(0);
  };

  stage(0, 0);
  stage(1, 1);
  __syncthreads();                    // qs visible (also drains vmcnt)

  for (int kt = 0; kt < 16; ++kt) {
    if (kt < 14) {
      stage(kt + 2, (kt + 2) & 3);
      asm volatile("s_waitcnt vmcnt(8)" ::: "memory");  // stage(kt) landed
    } else if (kt == 14) {
      asm volatile("s_waitcnt vmcnt(4)" ::: "memory");
    } else {
      asm volatile("s_waitcnt vmcnt(0)" ::: "memory");
    }
    __builtin_amdgcn_s_barrier();     // buf[kt&3] staged for all waves;
                                      // also: all reads of buf[(kt+2)&3] done
    mfma_kt(kt, kt & 3);
  }

  // ---- per-row epilogue (called twice; static indexing via reference) ----
  auto epilogue = [&](f32x4 (&acc)[4][4], int gid) {
    // max: core (regs) + border (global)
    float m = -3e38f;
    #pragma unroll
    for (int i = 0; i < 4; ++i)
      #pragma unroll
      for (int j = 0; j < 4; ++j)
        #pragma unroll
        for (int r = 0; r < 4; ++r) m = fmaxf(m, acc[i][j][r]);
    #pragma unroll
    for (int off = 32; off > 0; off >>= 1) m = fmaxf(m, __shfl_xor(m, off));
    if (lane == 0) redA[w] = m;

    const float* SbT = Sb + (size_t)gid*RPAD;
    const float* SbS = Sb + (size_t)MQ*RPAD + (size_t)gid*RPAD;
    const float btv = (tid < 129) ? SbT[tid] : -3e38f;
    const float bsv = (tid < 128) ? SbS[tid] : -3e38f;
    float bm = fmaxf(btv, bsv);
    #pragma unroll
    for (int off = 32; off > 0; off >>= 1) bm = fmaxf(bm, __shfl_xor(bm, off));
    if (lane == 0) redB[w] = bm;
    __syncthreads();
    const float mraw = fmaxf(
        fmaxf(fmaxf(redA[0], redA[1]), fmaxf(redA[2], redA[3])),
        fmaxf(fmaxf(redB[0], redB[1]), fmaxf(redB[2], redB[3])));

    // exp core + core sum
    float csum = 0.f;
    #pragma unroll
    for (int i = 0; i < 4; ++i)
      #pragma unroll
      for (int j = 0; j < 4; ++j)
        #pragma unroll
        for (int r = 0; r < 4; ++r) {
          float p = exp2f((acc[i][j][r] - mraw) * SCLG2E);
          acc[i][j][r] = p;
          csum += p;
        }
    #pragma unroll
    for (int off = 32; off > 0; off >>= 1) csum += __shfl_xor(csum, off);
    if (lane == 0) redC[w] = csum;

    // row sums
    #pragma unroll
    for (int i = 0; i < 4; ++i) {
      #pragma unroll
      for (int r = 0; r < 4; ++r) {
        float rs = acc[i][0][r] + acc[i][1][r] + acc[i][2][r] + acc[i][3][r];
        rs += __shfl_xor(rs, 1); rs += __shfl_xor(rs, 2);
        rs += __shfl_xor(rs, 4); rs += __shfl_xor(rs, 8);
        if (fr == 0) wsA[cb][rb*64 + i*16 + fq*4 + r] = rs;
      }
    }
    // col sums
    #pragma unroll
    for (int j = 0; j < 4; ++j) {
      float cs = 0.f;
      #pragma unroll
      for (int i = 0; i < 4; ++i)
        #pragma unroll
        for (int r = 0; r < 4; ++r) cs += acc[i][j][r];
      cs += __shfl_xor(cs, 16); cs += __shfl_xor(cs, 32);
      if (fq == 0) wtA[rb][cb*64 + j*16 + fr] = cs;
    }

    // border exps + sums
    const float pbt = (tid < 129) ? exp2f((btv - mraw) * SCLG2E) : 0.f;
    const float pbs = (tid < 128) ? exp2f((bsv - mraw) * SCLG2E) : 0.f;
    float sbt = pbt, sbs = pbs;
    #pragma unroll
    for (int off = 32; off > 0; off >>= 1) {
      sbt += __shfl_xor(sbt, off);
      sbs += __shfl_xor(sbs, off);
    }
    if (lane == 0) { redD[w] = sbt; redE[w] = sbs; }
    if (tid == 128) cornerP = pbt;
    __syncthreads();

    const float pbt_sum = redD[0] + redD[1] + redD[2] + redD[3];
    const float pbs_sum = redE[0] + redE[1] + redE[2] + redE[3];
    const float core_sum = redC[0] + redC[1] + redC[2] + redC[3];
    const float invZ = 1.0f / (core_sum + pbt_sum + pbs_sum);

    if (tid < WPAD) {
      float wsv = (tid < 128) ? (wsA[0][tid] + wsA[1][tid] + pbs)
                : (tid == 128) ? pbt_sum : 0.f;
      float wtv = (tid < 128) ? (wtA[0][tid] + wtA[1][tid] + pbt)
                : (tid == 128) ? (pbs_sum + cornerP) : 0.f;
      wsn[(size_t)gid*WPAD + tid] = (f16)(wsv * invZ);
      wtn[(size_t)gid*WPAD + tid] = (f16)(wtv * invZ);
    }
  };

  epilogue(acc0, gid0);
  __syncthreads();                    // protect shared reduction arrays
  epilogue(acc1, gid0 + 1);
}

// ---------------------------------------------------------------------------
// ctx GEMM: sctx[l][hd] = sum_s wsn[l][s] * skey[s][hd]  (keyT pre-transposed)
// ---------------------------------------------------------------------------
__global__ __launch_bounds__(256) void ctx_gemm(
    const f16* __restrict__ wsn, const f16* __restrict__ wtn,
    const f16* __restrict__ skeyT, const f16* __restrict__ tkeyT,
    f16* __restrict__ sctx, f16* __restrict__ tctx)
{
  __shared__ __align__(16) f16 As[64*168];
  __shared__ __align__(16) f16 Bs[64*168];
  const int z = blockIdx.x & 1, b = blockIdx.x >> 1;
  const int mt = blockIdx.y, nt = blockIdx.z;
  const int tid = threadIdx.x, lane = tid & 63, w = tid >> 6;
  const int wr = w & 1, wc = w >> 1;
  const int fq = lane >> 4, fr = lane & 15;

  const f16* A  = (z ? wtn : wsn) + ((size_t)b*256 + mt*64)*WPAD;
  const f16* Bt = (z ? tkeyT : skeyT) + ((size_t)b*512 + nt*64)*WPAD;

  for (int t = tid; t < 1280; t += 256) {
    int r = t / 20, c = t % 20;
    *(uint4*)(&As[r*168 + c*8]) = *(const uint4*)(A + (size_t)r*WPAD + c*8);
    *(uint4*)(&Bs[r*168 + c*8]) = *(const uint4*)(Bt + (size_t)r*WPAD + c*8);
  }
  __syncthreads();

  f32x4 acc[2][2] = {};
  #pragma unroll
  for (int ks = 0; ks < 5; ++ks) {
    f16x8 af[2], bf_[2];
    #pragma unroll
    for (int i = 0; i < 2; ++i) {
      af[i]  = *(const f16x8*)(&As[(wr*32 + i*16 + fr)*168 + ks*32 + fq*8]);
      bf_[i] = *(const f16x8*)(&Bs[(wc*32 + i*16 + fr)*168 + ks*32 + fq*8]);
    }
    #pragma unroll
    for (int i = 0; i < 2; ++i)
      #pragma unroll
      for (int j = 0; j < 2; ++j)
        acc[i][j] = __builtin_amdgcn_mfma_f32_16x16x32_f16(af[i], bf_[j], acc[i][j], 0, 0, 0);
  }

  f16* out = z ? tctx : sctx;
  #pragma unroll
  for (int i = 0; i < 2; ++i)
    #pragma unroll
    for (int j = 0; j < 2; ++j) {
      int col = nt*64 + wc*32 + j*16 + fr;
      #pragma unroll
      for (int r = 0; r < 4; ++r) {
        int row = b*256 + mt*64 + wr*32 + i*16 + fq*4 + r;
        out[(size_t)row*HD + col] = (f16)acc[i][j][r];
      }
    }
}

// ---------------------------------------------------------------------------
// out = tanh([query(f32) | sctx | tctx] @ WoT^T + bo), K = 1536, f32 out.
// ---------------------------------------------------------------------------
__global__ __launch_bounds__(256) void gemm_out(
    const float* __restrict__ query, const f16* __restrict__ sctx,
    const f16* __restrict__ tctx, const f16* __restrict__ WoT,
    const float* __restrict__ bias, float* __restrict__ C)
{
  __shared__ __align__(16) f16 As[64*64];
  __shared__ __align__(16) f16 Bs[64*64];
  const int tid  = threadIdx.x;
  const int lane = tid & 63;
  const int w    = tid >> 6;
  const int wr   = w & 1, wc = w >> 1;
  const int fq   = lane >> 4, fr = lane & 15;
  const int bm = blockIdx.x * 64, bn = blockIdx.y * 64;

  f32x4 acc[2][2] = {};

  for (int k0 = 0; k0 < 1536; k0 += 64) {
    const int seg  = k0 >> 9;
    const int kloc = k0 & 511;
    #pragma unroll
    for (int i = 0; i < 2; ++i) {
      int idx = tid + 256*i;
      int r = idx >> 3, c = idx & 7;
      int o = ((r << 7) + (c << 4)) ^ ((r & 7) << 4);
      if (seg == 0) {
        const float* ap = query + (size_t)(bm + r)*512 + kloc + c*8;
        float4 x0 = *(const float4*)ap;
        float4 x1 = *(const float4*)(ap + 4);
        f16x8 va = { (f16)x0.x, (f16)x0.y, (f16)x0.z, (f16)x0.w,
                     (f16)x1.x, (f16)x1.y, (f16)x1.z, (f16)x1.w };
        *(f16x8*)((char*)As + o) = va;
      } else {
        const f16* Ap = (seg == 1) ? sctx : tctx;
        *(uint4*)((char*)As + o) = *(const uint4*)(Ap + (size_t)(bm + r)*512 + kloc + c*8);
      }
      *(uint4*)((char*)Bs + o) = *(const uint4*)(WoT + (size_t)(bn + r)*1536 + k0 + c*8);
    }
    __syncthreads();
    #pragma unroll
    for (int ks = 0; ks < 2; ++ks) {
      f16x8 af[2], bf_[2];
      #pragma unroll
      for (int i = 0; i < 2; ++i) {
        int ra = wr*32 + i*16 + fr;
        int oa = ((ra << 7) + (ks << 6) + (fq << 4)) ^ ((ra & 7) << 4);
        af[i] = *(const f16x8*)((const char*)As + oa);
        int rb = wc*32 + i*16 + fr;
        int ob = ((rb << 7) + (ks << 6) + (fq << 4)) ^ ((rb & 7) << 4);
        bf_[i] = *(const f16x8*)((const char*)Bs + ob);
      }
      #pragma unroll
      for (int i = 0; i < 2; ++i)
        #pragma unroll
        for (int j = 0; j < 2; ++j)
          acc[i][j] = __builtin_amdgcn_mfma_f32_16x16x32_f16(af[i], bf_[j], acc[i][j], 0, 0, 0);
    }
    __syncthreads();
  }

  #pragma unroll
  for (int i = 0; i < 2; ++i)
    #pragma unroll
    for (int j = 0; j < 2; ++j) {
      int n = bn + wc*32 + j*16 + fr;
      float bv = bias[n];
      #pragma unroll
      for (int r = 0; r < 4; ++r) {
        int m = bm + wr*32 + i*16 + fq*4 + r;
        float xx = acc[i][j][r] + bv;
        xx = fminf(fmaxf(xx, -20.f), 20.f);
        float e = exp2f(TANH2E * xx);
        C[(size_t)m*HD + n] = (e - 1.0f) / (e + 1.0f);
      }
    }
}

extern "C" void kernel_launch(void* const* d_in, const int* in_sizes, int n_in,
                              void* d_out, int out_size, void* d_ws, size_t ws_size,
                              hipStream_t stream) {
  (void)in_sizes; (void)n_in; (void)out_size; (void)ws_size;
  const float* query = (const float*)d_in[0];
  const float* src   = (const float*)d_in[1];
  const float* trg   = (const float*)d_in[2];
  const float* Wq    = (const float*)d_in[3];
  const float* bq    = (const float*)d_in[4];
  const float* Wsm   = (const float*)d_in[5];
  const float* bs    = (const float*)d_in[6];
  const float* Wtm   = (const float*)d_in[7];
  const float* bt    = (const float*)d_in[8];
  const float* Wo    = (const float*)d_in[9];
  const float* bo    = (const float*)d_in[10];
  float* out = (float*)d_out;

  // workspace layout (~32 MB)
  char* p = (char*)d_ws;
  f16* WqT   = (f16*)p;  p += (size_t)HD*HD*2;
  f16* WsT   = (f16*)p;  p += (size_t)HD*HD*2;
  f16* WtT   = (f16*)p;  p += (size_t)HD*HD*2;
  f16* WoT   = (f16*)p;  p += (size_t)1536*HD*2;
  f16* q_h   = (f16*)p;  p += (size_t)MQ*HD*2;
  f16* skey  = (f16*)p;  p += (size_t)NBATCH*RPAD*HD*2;
  f16* tkey  = (f16*)p;  p += (size_t)NBATCH*RPAD*HD*2;
  f16* skeyT = (f16*)p;  p += (size_t)NBATCH*HD*WPAD*2;
  f16* tkeyT = (f16*)p;  p += (size_t)NBATCH*HD*WPAD*2;
  f16* wsn   = (f16*)p;  p += (size_t)MQ*WPAD*2;
  f16* wtn   = (f16*)p;  p += (size_t)MQ*WPAD*2;
  f16* sctx  = (f16*)p;  p += (size_t)MQ*HD*2;
  f16* tctx  = (f16*)p;  p += (size_t)MQ*HD*2;
  float* Sb  = (float*)p; p += (size_t)2*MQ*RPAD*4;

  dim3 blk(256);
  prep_kernel<<<dim3(416), blk, 0, stream>>>(Wq, Wsm, Wtm, Wo, bs, bt,
                                             WqT, WsT, WtT, WoT,
                                             skey, tkey, skeyT, tkeyT);
  gemm_in<<<dim3(128, 8), blk, 0, stream>>>(query, src, trg, WqT, WsT, WtT,
                                            bq, bs, bt, q_h, skey, tkey,
                                            skeyT, tkeyT);
  border_kernel<<<dim3(128), blk, 0, stream>>>(q_h, skey, tkey, Sb);
  attn_core<<<dim3(MQ/2), blk, 0, stream>>>(q_h, skey, tkey, Sb, wsn, wtn);
  ctx_gemm<<<dim3(32, 4, 8), blk, 0, stream>>>(wsn, wtn, skeyT, tkeyT, sctx, tctx);
  gemm_out<<<dim3(64, 8), blk, 0, stream>>>(query, sctx, tctx, WoT, bo, out);
}